// Round 6
// baseline (1909.775 us; speedup 1.0000x reference)
//
#include <hip/hip_runtime.h>
#include <hip/hip_bf16.h>

#define N_ENT 100000
#define HDIM 128
#define NE 200000
#define NR 460
#define NSTEP 4
#define SLOPE 0.22916666666666666f

typedef __attribute__((ext_vector_type(8))) short short8;
typedef __attribute__((ext_vector_type(4))) float f32x4;

__device__ __forceinline__ float sigm(float x) { return 1.0f / (1.0f + __expf(-x)); }
__device__ __forceinline__ short f2bs(float f) {
    __hip_bfloat16 b = __float2bfloat16(f);
    short s; __builtin_memcpy(&s, &b, 2); return s;
}

// ---------------------------------------------------------------------------
__global__ void zero_kernel(float* __restrict__ p, long n)
{
    long i = (long)blockIdx.x * 256 + threadIdx.x;
    if (i < n) p[i] = 0.0f;
}

__global__ void diag_kernel(float* o, float v)
{
    if (threadIdx.x == 0) o[0] = v;
}

// ---------------------------------------------------------------------------
// Prep: GRU weight transposes (f32) + bf16 B^T-layout buffers for the MFMA
// GEMMs.  BT[n][k] so that C[row,n] = sum_k A[row,k]*BT[n][k].
// ---------------------------------------------------------------------------
__global__ void prep_kernel(
    const float* __restrict__ emb_rel,
    const float* __restrict__ Wx, const float* __restrict__ Wh,
    const float* __restrict__ Wn1, const float* __restrict__ Wl1,
    const float* __restrict__ Wn2, const float* __restrict__ Wl2,
    const float* __restrict__ tgW, const float* __restrict__ gateW,
    const float* __restrict__ tdW,
    float* __restrict__ rel,
    float* __restrict__ WxT, float* __restrict__ WhT,
    short* __restrict__ BT1, short* __restrict__ BT2,
    short* __restrict__ BTe1, short* __restrict__ BTe2,
    short* __restrict__ BTe3)
{
    int tid = blockIdx.x * blockDim.x + threadIdx.x;
    int nthr = gridDim.x * blockDim.x;
    for (int i = tid; i < NR * HDIM; i += nthr)
        rel[i] = emb_rel[i];
    for (int i = tid; i < 384 * 256; i += nthr) {   // Wx (384,256) -> WxT
        int r = i >> 8, c = i & 255;
        WxT[c * 384 + r] = Wx[i];
    }
    for (int i = tid; i < 384 * 128; i += nthr) {   // Wh (384,128) -> WhT
        int r = i >> 7, c = i & 127;
        WhT[c * 384 + r] = Wh[i];
    }
    for (int i = tid; i < 128 * 256; i += nthr) {   // layer BTs: [x|h]@[Wn;Wl]
        int n = i >> 8, k = i & 255;
        float v1 = (k < 128) ? Wn1[k * 128 + n] : Wl1[(k - 128) * 128 + n];
        float v2 = (k < 128) ? Wn2[k * 128 + n] : Wl2[(k - 128) * 128 + n];
        BT1[n * 256 + k] = f2bs(v1);
        BT2[n * 256 + k] = f2bs(v2);
    }
    for (int i = tid; i < 128 * 128; i += nthr) {   // E1: cur_n @ tgW (transpose)
        int n = i >> 7, k = i & 127;                 // E3: d @ tdW.T (direct)
        BTe1[n * 128 + k] = f2bs(tgW[k * 128 + n]);
        BTe3[n * 128 + k] = f2bs(tdW[n * 128 + k]);
    }
    for (int i = tid; i < 128 * 256; i += nthr) {   // E2: [h1|h] @ gateW.T (direct)
        int n = i >> 8, k = i & 255;
        BTe2[n * 256 + k] = f2bs(gateW[n * 256 + k]);
    }
}

// ---------------------------------------------------------------------------
// h0 = l2norm(dynamic_emb); one wave per row.
// ---------------------------------------------------------------------------
__global__ __launch_bounds__(64)
void norm_init_kernel(const float* __restrict__ emb, float* __restrict__ h)
{
    int row = blockIdx.x, lane = threadIdx.x;
    float v0 = emb[row * HDIM + lane];
    float v1 = emb[row * HDIM + 64 + lane];
    float s = v0 * v0 + v1 * v1;
    #pragma unroll
    for (int off = 32; off; off >>= 1) s += __shfl_xor(s, off);
    float invn = 1.0f / fmaxf(sqrtf(s), 1e-12f);
    h[row * HDIM + lane] = v0 * invn;
    h[row * HDIM + 64 + lane] = v1 * invn;
}

// ---------------------------------------------------------------------------
// GRUCell relation evolution (f32 GEMV — tiny: 460 rows).
// ---------------------------------------------------------------------------
__global__ __launch_bounds__(128)
void gru_kernel(float* rel, const float* __restrict__ emb_rel,
                const float* __restrict__ WxT, const float* __restrict__ WhT,
                const float* __restrict__ bx, const float* __restrict__ bh)
{
    __shared__ __align__(16) float x[256];
    __shared__ __align__(16) float hh[128];
    int b = blockIdx.x, j = threadIdx.x;
    float hj = rel[b * HDIM + j];
    x[j] = emb_rel[b * HDIM + j];
    x[128 + j] = hj;
    hh[j] = hj;
    __syncthreads();
    float xr = 0, xz = 0, xn = 0, hr = 0, hz = 0, hn = 0;
    for (int k = 0; k < 256; k++) {
        float xv = x[k];
        const float* w = &WxT[k * 384];
        xr += xv * w[j]; xz += xv * w[128 + j]; xn += xv * w[256 + j];
    }
    for (int k = 0; k < 128; k++) {
        float hv = hh[k];
        const float* w = &WhT[k * 384];
        hr += hv * w[j]; hz += hv * w[128 + j]; hn += hv * w[256 + j];
    }
    float r = sigm(xr + bx[j] + hr + bh[j]);
    float z = sigm(xz + bx[128 + j] + hz + bh[128 + j]);
    float n = tanhf(xn + bx[256 + j] + r * (hn + bh[256 + j]));
    rel[b * HDIM + j] = (1.0f - z) * n + z * hj;
}

// ---------------------------------------------------------------------------
// Edge scatter for dst-chunk [lo,hi): agg[(dst-lo)] += hin[src] + rel[etype].
// ---------------------------------------------------------------------------
__global__ __launch_bounds__(256)
void scatter_kernel(const int* __restrict__ src, const int* __restrict__ dst,
                    const int* __restrict__ et,
                    const float* __restrict__ hin, const float* __restrict__ rel,
                    float* __restrict__ agg, float* __restrict__ deg,
                    int lo, int hi, int do_deg)
{
    int idx = blockIdx.x * 256 + threadIdx.x;
    int e = idx >> 7;
    int i = idx & 127;
    int d = dst[e];
    if (d < lo || d >= hi) return;
    int s = src[e], r = et[e];
    float v = hin[s * HDIM + i] + rel[r * HDIM + i];
    atomicAdd(&agg[(long)(d - lo) * HDIM + i], v);
    if (do_deg && i == 0) atomicAdd(&deg[d], 1.0f);
}

// ---------------------------------------------------------------------------
// Layer MFMA GEMM (MODE 0 of round-5 template, kept identical):
// out = rrelu([agg*rdeg | h] @ BT^T), re-zeroes agg (+deg if zdeg).
// ---------------------------------------------------------------------------
template<int MODE, int KT>
__global__ __launch_bounds__(256, 2)
void gemm_kernel(const float* __restrict__ A1, const float* __restrict__ A2,
                 float* __restrict__ scl, const short* __restrict__ BTg,
                 const float* __restrict__ bias,
                 float* __restrict__ out0, float* __restrict__ x0,
                 const float* __restrict__ x1,
                 int lo, int hi, int zdeg)
{
    __shared__ short bt[128][KT + 8];
    const int tid = threadIdx.x;
    for (int i = tid * 8; i < 128 * KT; i += 256 * 8) {
        int n = i / KT, k = i % KT;
        *(short8*)&bt[n][k] = *(const short8*)&BTg[i];
    }
    __syncthreads();

    const int lane = tid & 63;
    const int wv = tid >> 6;
    const int m = lane & 15, q = lane >> 4;
    const int rowBase = lo + blockIdx.x * 256 + wv * 64;

    f32x4 acc[4][8];
    #pragma unroll
    for (int rt = 0; rt < 4; rt++)
        #pragma unroll
        for (int ct = 0; ct < 8; ct++)
            acc[rt][ct] = (f32x4)0.0f;

    float rs[4];
    #pragma unroll
    for (int rt = 0; rt < 4; rt++) {
        int row = rowBase + rt * 16 + m;
        rs[rt] = (row < hi) ? 1.0f / fmaxf(scl[row], 1.0f) : 0.0f;
    }

    for (int kc = 0; kc < KT / 32; kc++) {
        short8 a[4];
        #pragma unroll
        for (int rt = 0; rt < 4; rt++) {
            int row = rowBase + rt * 16 + m;
            float v[8];
            if (row < hi) {
                int k0 = kc * 32 + q * 8;
                const float* p = (kc < 4) ? &A1[(long)(row - lo) * HDIM + k0]
                                          : &A2[(long)row * HDIM + (k0 - 128)];
                float4 u0 = *(const float4*)p;
                float4 u1 = *(const float4*)(p + 4);
                v[0]=u0.x; v[1]=u0.y; v[2]=u0.z; v[3]=u0.w;
                v[4]=u1.x; v[5]=u1.y; v[6]=u1.z; v[7]=u1.w;
                if (kc < 4) {
                    #pragma unroll
                    for (int i = 0; i < 8; i++) v[i] *= rs[rt];
                }
            } else {
                #pragma unroll
                for (int i = 0; i < 8; i++) v[i] = 0.0f;
            }
            short8 t;
            #pragma unroll
            for (int i = 0; i < 8; i++) t[i] = f2bs(v[i]);
            a[rt] = t;
        }
        short8 b[8];
        #pragma unroll
        for (int ct = 0; ct < 8; ct++)
            b[ct] = *(const short8*)&bt[ct * 16 + m][kc * 32 + q * 8];
        #pragma unroll
        for (int rt = 0; rt < 4; rt++)
            #pragma unroll
            for (int ct = 0; ct < 8; ct++)
                acc[rt][ct] = __builtin_amdgcn_mfma_f32_16x16x32_bf16(
                    a[rt], b[ct], acc[rt][ct], 0, 0, 0);
    }

    #pragma unroll
    for (int rt = 0; rt < 4; rt++) {
        #pragma unroll
        for (int rg = 0; rg < 4; rg++) {
            int row = rowBase + rt * 16 + q * 4 + rg;
            if (row >= hi) continue;
            #pragma unroll
            for (int ct = 0; ct < 8; ct++) {
                int col = ct * 16 + m;
                float c = acc[rt][ct][rg];
                long rc = (long)row * HDIM + col;
                c = c >= 0.0f ? c : SLOPE * c;
                out0[rc] = c;
                x0[(long)(row - lo) * HDIM + col] = 0.0f;   // re-zero agg
                if (zdeg && col == 0) scl[row] = 0.0f;      // re-zero deg
            }
        }
    }
}

// ---------------------------------------------------------------------------
// Fused epilogue: per 32-row block, all row-local:
//   invn = 1/||cur||;  E1: h1 = tw*cur_n + (1-tw)*h,  tw = sig(cur_n@Wt + bt)
//   E2: h2 = g*h1 + (1-g)*h,  g = sig([h1|h]@Wg^T + bg)
//   E3: out = h2 + relu((h2-h)@Wtd^T + btd)
// 128 thr = 2 waves, wave owns 16 rows (1 row-tile x 8 col-tiles 16x16x32).
// Intermediates in LDS (pad 128->132 floats).  B-frags read from global
// (L2-hot: every block reads the same 128 KB of weights).
// ---------------------------------------------------------------------------
__global__ __launch_bounds__(128)
void fused_epi_kernel(const float* __restrict__ cur, const float* __restrict__ hprev,
                      const short* __restrict__ BTe1, const short* __restrict__ BTe2,
                      const short* __restrict__ BTe3,
                      const float* __restrict__ bt, const float* __restrict__ bg,
                      const float* __restrict__ btd,
                      float* __restrict__ outp)
{
    __shared__ __align__(16) float cs[32 * 132];   // cur, later h2
    __shared__ __align__(16) float hs[32 * 132];   // h
    __shared__ __align__(16) float h1s[32 * 132];  // h1, later result
    __shared__ float invn_s[32];
    const int tid = threadIdx.x;
    const int row0 = blockIdx.x * 32;

    #pragma unroll
    for (int it = 0; it < 8; it++) {
        int idx = it * 128 + tid;
        int r = idx >> 5, c4 = (idx & 31) * 4;
        *(float4*)&cs[r * 132 + c4] = *(const float4*)&cur[(long)(row0 + r) * HDIM + c4];
        *(float4*)&hs[r * 132 + c4] = *(const float4*)&hprev[(long)(row0 + r) * HDIM + c4];
    }
    __syncthreads();

    const int wv = tid >> 6, lane = tid & 63;
    const int m = lane & 15, q = lane >> 4;
    const int wr0 = wv * 16;                   // wave's local row base

    // row inverse norms (wave's own 16 rows)
    for (int r = 0; r < 16; r++) {
        float a = cs[(wr0 + r) * 132 + lane];
        float b = cs[(wr0 + r) * 132 + 64 + lane];
        float s = a * a + b * b;
        #pragma unroll
        for (int off = 32; off; off >>= 1) s += __shfl_xor(s, off);
        if (lane == 0) invn_s[wr0 + r] = 1.0f / fmaxf(sqrtf(s), 1e-12f);
    }
    __syncthreads();

    const float sA = invn_s[wr0 + m];

    // ---- E1: tw = sig(cur_n @ Wt + bt); h1 = tw*cur_n + (1-tw)*h
    f32x4 acc[8];
    #pragma unroll
    for (int ct = 0; ct < 8; ct++) acc[ct] = (f32x4)0.0f;
    #pragma unroll
    for (int kc = 0; kc < 4; kc++) {
        int k0 = kc * 32 + q * 8;
        const float* p = &cs[(wr0 + m) * 132 + k0];
        short8 a;
        #pragma unroll
        for (int j = 0; j < 8; j++) a[j] = f2bs(p[j] * sA);
        #pragma unroll
        for (int ct = 0; ct < 8; ct++) {
            short8 b = *(const short8*)&BTe1[(ct * 16 + m) * 128 + k0];
            acc[ct] = __builtin_amdgcn_mfma_f32_16x16x32_bf16(a, b, acc[ct], 0, 0, 0);
        }
    }
    #pragma unroll
    for (int ct = 0; ct < 8; ct++) {
        int col = ct * 16 + m;
        #pragma unroll
        for (int rg = 0; rg < 4; rg++) {
            int rl = wr0 + q * 4 + rg;
            float tw = sigm(acc[ct][rg] + bt[col]);
            float curn = cs[rl * 132 + col] * invn_s[rl];
            float hv = hs[rl * 132 + col];
            h1s[rl * 132 + col] = tw * curn + (1.0f - tw) * hv;
        }
    }
    __syncthreads();

    // ---- E2: g = sig([h1|h] @ Wg^T + bg); h2 = g*h1 + (1-g)*h  -> cs
    #pragma unroll
    for (int ct = 0; ct < 8; ct++) acc[ct] = (f32x4)0.0f;
    #pragma unroll
    for (int kc = 0; kc < 8; kc++) {
        int k0 = kc * 32 + q * 8;
        const float* p = (kc < 4) ? &h1s[(wr0 + m) * 132 + k0]
                                  : &hs[(wr0 + m) * 132 + (k0 - 128)];
        short8 a;
        #pragma unroll
        for (int j = 0; j < 8; j++) a[j] = f2bs(p[j]);
        #pragma unroll
        for (int ct = 0; ct < 8; ct++) {
            short8 b = *(const short8*)&BTe2[(ct * 16 + m) * 256 + k0];
            acc[ct] = __builtin_amdgcn_mfma_f32_16x16x32_bf16(a, b, acc[ct], 0, 0, 0);
        }
    }
    #pragma unroll
    for (int ct = 0; ct < 8; ct++) {
        int col = ct * 16 + m;
        #pragma unroll
        for (int rg = 0; rg < 4; rg++) {
            int rl = wr0 + q * 4 + rg;
            float g = sigm(acc[ct][rg] + bg[col]);
            cs[rl * 132 + col] = g * h1s[rl * 132 + col]
                               + (1.0f - g) * hs[rl * 132 + col];
        }
    }
    __syncthreads();

    // ---- E3: out = h2 + relu((h2-h) @ Wtd^T + btd)  -> h1s, then copy out
    #pragma unroll
    for (int ct = 0; ct < 8; ct++) acc[ct] = (f32x4)0.0f;
    #pragma unroll
    for (int kc = 0; kc < 4; kc++) {
        int k0 = kc * 32 + q * 8;
        const float* pc = &cs[(wr0 + m) * 132 + k0];
        const float* ph = &hs[(wr0 + m) * 132 + k0];
        short8 a;
        #pragma unroll
        for (int j = 0; j < 8; j++) a[j] = f2bs(pc[j] - ph[j]);
        #pragma unroll
        for (int ct = 0; ct < 8; ct++) {
            short8 b = *(const short8*)&BTe3[(ct * 16 + m) * 128 + k0];
            acc[ct] = __builtin_amdgcn_mfma_f32_16x16x32_bf16(a, b, acc[ct], 0, 0, 0);
        }
    }
    #pragma unroll
    for (int ct = 0; ct < 8; ct++) {
        int col = ct * 16 + m;
        #pragma unroll
        for (int rg = 0; rg < 4; rg++) {
            int rl = wr0 + q * 4 + rg;
            float td = fmaxf(acc[ct][rg] + btd[col], 0.0f);
            h1s[rl * 132 + col] = cs[rl * 132 + col] + td;
        }
    }
    __syncthreads();

    #pragma unroll
    for (int it = 0; it < 8; it++) {
        int idx = it * 128 + tid;
        int r = idx >> 5, c4 = (idx & 31) * 4;
        *(float4*)&outp[(long)(row0 + r) * HDIM + c4] = *(float4*)&h1s[r * 132 + c4];
    }
}

// ---------------------------------------------------------------------------
extern "C" void kernel_launch(void* const* d_in, const int* in_sizes, int n_in,
                              void* d_out, int out_size, void* d_ws, size_t ws_size,
                              hipStream_t stream)
{
    const int* src = (const int*)d_in[0];
    const int* dst = (const int*)d_in[1];
    const int* ety = (const int*)d_in[2];
    const float* dyn     = (const float*)d_in[3];
    const float* emb_rel = (const float*)d_in[4];
    const float* Wn1     = (const float*)d_in[5];
    const float* Wl1     = (const float*)d_in[6];
    const float* Wn2     = (const float*)d_in[7];
    const float* Wl2     = (const float*)d_in[8];
    const float* gWx     = (const float*)d_in[9];
    const float* gWh     = (const float*)d_in[10];
    const float* gbx     = (const float*)d_in[11];
    const float* gbh     = (const float*)d_in[12];
    const float* gateW   = (const float*)d_in[13];
    const float* gateb   = (const float*)d_in[14];
    const float* tdW     = (const float*)d_in[15];
    const float* tdb     = (const float*)d_in[16];
    const float* tgW     = (const float*)d_in[17];
    const float* tgb     = (const float*)d_in[18];

    const long NH = (long)N_ENT * HDIM;          // 12,800,000
    float* ws = (float*)d_ws;
    long off = 0;
    float* A    = ws + off; off += NH;           // h state
    float* B    = ws + off; off += NH;           // layer1 out
    float* rel  = ws + off; off += (long)NR * HDIM;
    float* WxT  = ws + off; off += 98304;
    float* WhT  = ws + off; off += 49152;
    short* BT1  = (short*)(ws + off); off += 16384;   // 128x256 bf16
    short* BT2  = (short*)(ws + off); off += 16384;
    short* BTe1 = (short*)(ws + off); off += 8192;    // 128x128 bf16
    short* BTe2 = (short*)(ws + off); off += 16384;
    short* BTe3 = (short*)(ws + off); off += 8192;
    float* deg  = ws + off; off += 100352;
    float* agg  = ws + off;                      // chunk*128 floats
    float* C    = (float*)d_out;                 // layer2 out (= cur)

    const long avail = (long)(ws_size / 4) - off;
    const int cand[5] = {100000, 50000, 25008, 12512, 6256};
    int chunk = -1;
    for (int c = 0; c < 5; c++)
        if (avail >= (long)cand[c] * HDIM) { chunk = cand[c]; break; }

    if (chunk < 0) {
        diag_kernel<<<1, 64, 0, stream>>>((float*)d_out, (float)ws_size);
        return;
    }

    {   // zero deg + agg (contiguous)
        long nz = 100352 + (long)chunk * HDIM;
        zero_kernel<<<(int)((nz + 255) / 256), 256, 0, stream>>>(deg, nz);
    }

    prep_kernel<<<256, 256, 0, stream>>>(
        emb_rel, gWx, gWh, Wn1, Wl1, Wn2, Wl2, tgW, gateW, tdW,
        rel, WxT, WhT, BT1, BT2, BTe1, BTe2, BTe3);

    norm_init_kernel<<<N_ENT, 64, 0, stream>>>(dyn, A);

    const int scatter_grid = NE * HDIM / 256;    // 100000 blocks
    const int fe_grid = N_ENT / 32;              // 3125 blocks

    for (int t = 0; t < NSTEP; t++) {
        const int* st = src + (long)t * NE;
        const int* dt = dst + (long)t * NE;
        const int* et = ety + (long)t * NE;

        gru_kernel<<<NR, 128, 0, stream>>>(rel, emb_rel, WxT, WhT, gbx, gbh);

        // layer 1: A -> B
        for (int lo = 0; lo < N_ENT; lo += chunk) {
            int hi = lo + chunk > N_ENT ? N_ENT : lo + chunk;
            scatter_kernel<<<scatter_grid, 256, 0, stream>>>(
                st, dt, et, A, rel, agg, deg, lo, hi, 1);
            gemm_kernel<0, 256><<<(hi - lo + 255) / 256, 256, 0, stream>>>(
                agg, A, deg, BT1, nullptr, B, agg, nullptr, lo, hi, 0);
        }
        // layer 2: B -> C (re-zeroes deg for next step)
        for (int lo = 0; lo < N_ENT; lo += chunk) {
            int hi = lo + chunk > N_ENT ? N_ENT : lo + chunk;
            scatter_kernel<<<scatter_grid, 256, 0, stream>>>(
                st, dt, et, B, rel, agg, deg, lo, hi, 0);
            gemm_kernel<0, 256><<<(hi - lo + 255) / 256, 256, 0, stream>>>(
                agg, B, deg, BT2, nullptr, C, agg, nullptr, lo, hi, 1);
        }

        // fused epilogue: (C, A) -> A (t<3) or d_out == C (t=3)
        float* outp = (t == NSTEP - 1) ? C : A;
        fused_epi_kernel<<<fe_grid, 128, 0, stream>>>(
            C, A, BTe1, BTe2, BTe3, tgb, gateb, tdb, outp);
    }
}

// Round 7
// 1784.280 us; speedup vs baseline: 1.0703x; 1.0703x over previous
//
#include <hip/hip_runtime.h>
#include <hip/hip_bf16.h>

#define N_ENT 100000
#define HDIM 128
#define NE 200000
#define NR 460
#define NSTEP 4
#define SLOPE 0.22916666666666666f
#define NPAD 100352            // N_ENT padded to 1024 multiple (98*1024)
#define SCAN_NB 98

typedef __attribute__((ext_vector_type(8))) short short8;
typedef __attribute__((ext_vector_type(4))) float f32x4;

__device__ __forceinline__ float sigm(float x) { return 1.0f / (1.0f + __expf(-x)); }
__device__ __forceinline__ short f2bs(float f) {
    __hip_bfloat16 b = __float2bfloat16(f);
    short s; __builtin_memcpy(&s, &b, 2); return s;
}

// ---------------------------------------------------------------------------
__global__ void zero_int_kernel(int* __restrict__ p, int n)
{
    int i = blockIdx.x * 256 + threadIdx.x;
    if (i < n) p[i] = 0;
}

__global__ void diag_kernel(float* o, float v)
{
    if (threadIdx.x == 0) o[0] = v;
}

// ---------------------------------------------------------------------------
// CSR build: histogram -> 3-phase exclusive scan -> fill
// ---------------------------------------------------------------------------
__global__ void hist_kernel(const int* __restrict__ dst, int* __restrict__ cnt)
{
    int e = blockIdx.x * 256 + threadIdx.x;
    if (e < NE) atomicAdd(&cnt[dst[e]], 1);
}

// 1024 elems/block: per-thread 4-elem serial + 256-wide LDS scan
__global__ __launch_bounds__(256)
void scan1_kernel(const int* __restrict__ cnt, int* __restrict__ rowptr,
                  int* __restrict__ bsum)
{
    __shared__ int ts[256];
    int b = blockIdx.x, t = threadIdx.x;
    int base = b * 1024 + t * 4;
    int4 v = *(const int4*)&cnt[base];
    int s = v.x + v.y + v.z + v.w;
    ts[t] = s;
    __syncthreads();
    for (int off = 1; off < 256; off <<= 1) {
        int x = 0;
        if (t >= off) x = ts[t - off];
        __syncthreads();
        if (t >= off) ts[t] += x;
        __syncthreads();
    }
    int excl = ts[t] - s;
    if (t == 255) bsum[b] = ts[t];
    rowptr[base + 0] = excl;
    rowptr[base + 1] = excl + v.x;
    rowptr[base + 2] = excl + v.x + v.y;
    rowptr[base + 3] = excl + v.x + v.y + v.z;
}

__global__ __launch_bounds__(128)
void scan2_kernel(int* __restrict__ bsum, int nb)
{
    __shared__ int ts[128];
    int t = threadIdx.x;
    int v = (t < nb) ? bsum[t] : 0;
    ts[t] = v;
    __syncthreads();
    for (int off = 1; off < 128; off <<= 1) {
        int x = 0;
        if (t >= off) x = ts[t - off];
        __syncthreads();
        if (t >= off) ts[t] += x;
        __syncthreads();
    }
    if (t < nb) bsum[t] = ts[t] - v;   // exclusive
}

__global__ __launch_bounds__(256)
void scan3_kernel(int* __restrict__ rowptr, const int* __restrict__ bsum)
{
    int b = blockIdx.x, t = threadIdx.x;
    int add = bsum[b];
    int base = b * 1024 + t * 4;
    rowptr[base + 0] += add;
    rowptr[base + 1] += add;
    rowptr[base + 2] += add;
    rowptr[base + 3] += add;
}

__global__ void fill_kernel(const int* __restrict__ dst,
                            const int* __restrict__ rowptr,
                            int* __restrict__ c2, int* __restrict__ eidx)
{
    int e = blockIdx.x * 256 + threadIdx.x;
    if (e < NE) {
        int d = dst[e];
        int p = atomicAdd(&c2[d], 1);
        eidx[rowptr[d] + p] = e;
    }
}

// ---------------------------------------------------------------------------
// Prep: GRU weight transposes (f32) + bf16 B^T buffers for the MFMA GEMMs.
// ---------------------------------------------------------------------------
__global__ void prep_kernel(
    const float* __restrict__ emb_rel,
    const float* __restrict__ Wx, const float* __restrict__ Wh,
    const float* __restrict__ Wn1, const float* __restrict__ Wl1,
    const float* __restrict__ Wn2, const float* __restrict__ Wl2,
    const float* __restrict__ tgW, const float* __restrict__ gateW,
    const float* __restrict__ tdW,
    float* __restrict__ rel,
    float* __restrict__ WxT, float* __restrict__ WhT,
    short* __restrict__ BT1, short* __restrict__ BT2,
    short* __restrict__ BTe1, short* __restrict__ BTe2,
    short* __restrict__ BTe3)
{
    int tid = blockIdx.x * blockDim.x + threadIdx.x;
    int nthr = gridDim.x * blockDim.x;
    for (int i = tid; i < NR * HDIM; i += nthr)
        rel[i] = emb_rel[i];
    for (int i = tid; i < 384 * 256; i += nthr) {
        int r = i >> 8, c = i & 255;
        WxT[c * 384 + r] = Wx[i];
    }
    for (int i = tid; i < 384 * 128; i += nthr) {
        int r = i >> 7, c = i & 127;
        WhT[c * 384 + r] = Wh[i];
    }
    for (int i = tid; i < 128 * 256; i += nthr) {   // layer BTs: [x|h]@[Wn;Wl]
        int n = i >> 8, k = i & 255;
        float v1 = (k < 128) ? Wn1[k * 128 + n] : Wl1[(k - 128) * 128 + n];
        float v2 = (k < 128) ? Wn2[k * 128 + n] : Wl2[(k - 128) * 128 + n];
        BT1[n * 256 + k] = f2bs(v1);
        BT2[n * 256 + k] = f2bs(v2);
    }
    for (int i = tid; i < 128 * 128; i += nthr) {   // E1 (transpose), E3 (direct)
        int n = i >> 7, k = i & 127;
        BTe1[n * 128 + k] = f2bs(tgW[k * 128 + n]);
        BTe3[n * 128 + k] = f2bs(tdW[n * 128 + k]);
    }
    for (int i = tid; i < 128 * 256; i += nthr) {   // E2 (direct)
        int n = i >> 8, k = i & 255;
        BTe2[n * 256 + k] = f2bs(gateW[n * 256 + k]);
    }
}

// ---------------------------------------------------------------------------
// h0 = l2norm(dynamic_emb); one wave per row.
// ---------------------------------------------------------------------------
__global__ __launch_bounds__(64)
void norm_init_kernel(const float* __restrict__ emb, float* __restrict__ h)
{
    int row = blockIdx.x, lane = threadIdx.x;
    float v0 = emb[row * HDIM + lane];
    float v1 = emb[row * HDIM + 64 + lane];
    float s = v0 * v0 + v1 * v1;
    #pragma unroll
    for (int off = 32; off; off >>= 1) s += __shfl_xor(s, off);
    float invn = 1.0f / fmaxf(sqrtf(s), 1e-12f);
    h[row * HDIM + lane] = v0 * invn;
    h[row * HDIM + 64 + lane] = v1 * invn;
}

// ---------------------------------------------------------------------------
// GRUCell relation evolution (f32 GEMV — tiny: 460 rows).
// ---------------------------------------------------------------------------
__global__ __launch_bounds__(128)
void gru_kernel(float* rel, const float* __restrict__ emb_rel,
                const float* __restrict__ WxT, const float* __restrict__ WhT,
                const float* __restrict__ bx, const float* __restrict__ bh)
{
    __shared__ __align__(16) float x[256];
    __shared__ __align__(16) float hh[128];
    int b = blockIdx.x, j = threadIdx.x;
    float hj = rel[b * HDIM + j];
    x[j] = emb_rel[b * HDIM + j];
    x[128 + j] = hj;
    hh[j] = hj;
    __syncthreads();
    float xr = 0, xz = 0, xn = 0, hr = 0, hz = 0, hn = 0;
    for (int k = 0; k < 256; k++) {
        float xv = x[k];
        const float* w = &WxT[k * 384];
        xr += xv * w[j]; xz += xv * w[128 + j]; xn += xv * w[256 + j];
    }
    for (int k = 0; k < 128; k++) {
        float hv = hh[k];
        const float* w = &WhT[k * 384];
        hr += hv * w[j]; hz += hv * w[128 + j]; hn += hv * w[256 + j];
    }
    float r = sigm(xr + bx[j] + hr + bh[j]);
    float z = sigm(xz + bx[128 + j] + hz + bh[128 + j]);
    float n = tanhf(xn + bx[256 + j] + r * (hn + bh[256 + j]));
    rel[b * HDIM + j] = (1.0f - z) * n + z * hj;
}

// ---------------------------------------------------------------------------
// CSR gather for rows [lo,hi): agg[r-lo] = (sum_e h[src]+rel[et]) / max(deg,1).
// One thread per (row, dim); 2 rows per 256-thread block.  No atomics.
// ---------------------------------------------------------------------------
__global__ __launch_bounds__(256)
void gather_kernel(const int* __restrict__ src, const int* __restrict__ et,
                   const int* __restrict__ eidx, const int* __restrict__ rowptr,
                   const float* __restrict__ hin, const float* __restrict__ rel,
                   float* __restrict__ agg, int lo, int hi)
{
    int idx = blockIdx.x * 256 + threadIdx.x;
    int r = lo + (idx >> 7);
    int i = idx & 127;
    if (r >= hi) return;
    int p0 = rowptr[r], p1 = rowptr[r + 1];
    float v = 0.0f;
    for (int p = p0; p < p1; p++) {
        int e = eidx[p];
        int s = src[e], rt = et[e];
        v += hin[(long)s * HDIM + i] + rel[rt * HDIM + i];
    }
    float rdeg = (p1 > p0) ? 1.0f / (float)(p1 - p0) : 0.0f;
    agg[(long)(r - lo) * HDIM + i] = v * rdeg;
}

// ---------------------------------------------------------------------------
// Layer MFMA GEMM: out = rrelu([agg | h] @ BT^T).  agg pre-normalized.
// 256 thr = 4 waves; wave owns 64 rows x 128 cols (16x16x32 MFMA tiles).
// ---------------------------------------------------------------------------
__global__ __launch_bounds__(256, 2)
void layer_gemm(const float* __restrict__ agg, const float* __restrict__ hin,
                const short* __restrict__ BTg, float* __restrict__ out,
                int lo, int hi)
{
    __shared__ short bt[128][264];     // 256 + 8 pad
    const int tid = threadIdx.x;
    for (int i = tid * 8; i < 128 * 256; i += 256 * 8) {
        int n = i >> 8, k = i & 255;
        *(short8*)&bt[n][k] = *(const short8*)&BTg[i];
    }
    __syncthreads();

    const int lane = tid & 63;
    const int wv = tid >> 6;
    const int m = lane & 15, q = lane >> 4;
    const int rowBase = lo + blockIdx.x * 256 + wv * 64;

    f32x4 acc[4][8];
    #pragma unroll
    for (int rt = 0; rt < 4; rt++)
        #pragma unroll
        for (int ct = 0; ct < 8; ct++)
            acc[rt][ct] = (f32x4)0.0f;

    for (int kc = 0; kc < 8; kc++) {
        short8 a[4];
        #pragma unroll
        for (int rt = 0; rt < 4; rt++) {
            int row = rowBase + rt * 16 + m;
            float v[8];
            if (row < hi) {
                int k0 = kc * 32 + q * 8;
                const float* p = (kc < 4) ? &agg[(long)(row - lo) * HDIM + k0]
                                          : &hin[(long)row * HDIM + (k0 - 128)];
                float4 u0 = *(const float4*)p;
                float4 u1 = *(const float4*)(p + 4);
                v[0]=u0.x; v[1]=u0.y; v[2]=u0.z; v[3]=u0.w;
                v[4]=u1.x; v[5]=u1.y; v[6]=u1.z; v[7]=u1.w;
            } else {
                #pragma unroll
                for (int i = 0; i < 8; i++) v[i] = 0.0f;
            }
            short8 t;
            #pragma unroll
            for (int i = 0; i < 8; i++) t[i] = f2bs(v[i]);
            a[rt] = t;
        }
        short8 b[8];
        #pragma unroll
        for (int ct = 0; ct < 8; ct++)
            b[ct] = *(const short8*)&bt[ct * 16 + m][kc * 32 + q * 8];
        #pragma unroll
        for (int rt = 0; rt < 4; rt++)
            #pragma unroll
            for (int ct = 0; ct < 8; ct++)
                acc[rt][ct] = __builtin_amdgcn_mfma_f32_16x16x32_bf16(
                    a[rt], b[ct], acc[rt][ct], 0, 0, 0);
    }

    #pragma unroll
    for (int rt = 0; rt < 4; rt++) {
        #pragma unroll
        for (int rg = 0; rg < 4; rg++) {
            int row = rowBase + rt * 16 + q * 4 + rg;
            if (row >= hi) continue;
            #pragma unroll
            for (int ct = 0; ct < 8; ct++) {
                int col = ct * 16 + m;
                float c = acc[rt][ct][rg];
                c = c >= 0.0f ? c : SLOPE * c;
                out[(long)row * HDIM + col] = c;
            }
        }
    }
}

// ---------------------------------------------------------------------------
// Fused epilogue (unchanged from round 6): l2norm + time-gate + GatedFusion
// + TemporalDifferenceFusion, 32 rows/block, 2 waves.
// ---------------------------------------------------------------------------
__global__ __launch_bounds__(128)
void fused_epi_kernel(const float* __restrict__ cur, const float* __restrict__ hprev,
                      const short* __restrict__ BTe1, const short* __restrict__ BTe2,
                      const short* __restrict__ BTe3,
                      const float* __restrict__ bt, const float* __restrict__ bg,
                      const float* __restrict__ btd,
                      float* __restrict__ outp)
{
    __shared__ __align__(16) float cs[32 * 132];   // cur, later h2
    __shared__ __align__(16) float hs[32 * 132];   // h
    __shared__ __align__(16) float h1s[32 * 132];  // h1, later result
    __shared__ float invn_s[32];
    const int tid = threadIdx.x;
    const int row0 = blockIdx.x * 32;

    #pragma unroll
    for (int it = 0; it < 8; it++) {
        int idx = it * 128 + tid;
        int r = idx >> 5, c4 = (idx & 31) * 4;
        *(float4*)&cs[r * 132 + c4] = *(const float4*)&cur[(long)(row0 + r) * HDIM + c4];
        *(float4*)&hs[r * 132 + c4] = *(const float4*)&hprev[(long)(row0 + r) * HDIM + c4];
    }
    __syncthreads();

    const int wv = tid >> 6, lane = tid & 63;
    const int m = lane & 15, q = lane >> 4;
    const int wr0 = wv * 16;

    for (int r = 0; r < 16; r++) {
        float a = cs[(wr0 + r) * 132 + lane];
        float b = cs[(wr0 + r) * 132 + 64 + lane];
        float s = a * a + b * b;
        #pragma unroll
        for (int off = 32; off; off >>= 1) s += __shfl_xor(s, off);
        if (lane == 0) invn_s[wr0 + r] = 1.0f / fmaxf(sqrtf(s), 1e-12f);
    }
    __syncthreads();

    const float sA = invn_s[wr0 + m];

    // E1
    f32x4 acc[8];
    #pragma unroll
    for (int ct = 0; ct < 8; ct++) acc[ct] = (f32x4)0.0f;
    #pragma unroll
    for (int kc = 0; kc < 4; kc++) {
        int k0 = kc * 32 + q * 8;
        const float* p = &cs[(wr0 + m) * 132 + k0];
        short8 a;
        #pragma unroll
        for (int j = 0; j < 8; j++) a[j] = f2bs(p[j] * sA);
        #pragma unroll
        for (int ct = 0; ct < 8; ct++) {
            short8 b = *(const short8*)&BTe1[(ct * 16 + m) * 128 + k0];
            acc[ct] = __builtin_amdgcn_mfma_f32_16x16x32_bf16(a, b, acc[ct], 0, 0, 0);
        }
    }
    #pragma unroll
    for (int ct = 0; ct < 8; ct++) {
        int col = ct * 16 + m;
        #pragma unroll
        for (int rg = 0; rg < 4; rg++) {
            int rl = wr0 + q * 4 + rg;
            float tw = sigm(acc[ct][rg] + bt[col]);
            float curn = cs[rl * 132 + col] * invn_s[rl];
            float hv = hs[rl * 132 + col];
            h1s[rl * 132 + col] = tw * curn + (1.0f - tw) * hv;
        }
    }
    __syncthreads();

    // E2
    #pragma unroll
    for (int ct = 0; ct < 8; ct++) acc[ct] = (f32x4)0.0f;
    #pragma unroll
    for (int kc = 0; kc < 8; kc++) {
        int k0 = kc * 32 + q * 8;
        const float* p = (kc < 4) ? &h1s[(wr0 + m) * 132 + k0]
                                  : &hs[(wr0 + m) * 132 + (k0 - 128)];
        short8 a;
        #pragma unroll
        for (int j = 0; j < 8; j++) a[j] = f2bs(p[j]);
        #pragma unroll
        for (int ct = 0; ct < 8; ct++) {
            short8 b = *(const short8*)&BTe2[(ct * 16 + m) * 256 + k0];
            acc[ct] = __builtin_amdgcn_mfma_f32_16x16x32_bf16(a, b, acc[ct], 0, 0, 0);
        }
    }
    #pragma unroll
    for (int ct = 0; ct < 8; ct++) {
        int col = ct * 16 + m;
        #pragma unroll
        for (int rg = 0; rg < 4; rg++) {
            int rl = wr0 + q * 4 + rg;
            float g = sigm(acc[ct][rg] + bg[col]);
            cs[rl * 132 + col] = g * h1s[rl * 132 + col]
                               + (1.0f - g) * hs[rl * 132 + col];
        }
    }
    __syncthreads();

    // E3
    #pragma unroll
    for (int ct = 0; ct < 8; ct++) acc[ct] = (f32x4)0.0f;
    #pragma unroll
    for (int kc = 0; kc < 4; kc++) {
        int k0 = kc * 32 + q * 8;
        const float* pc = &cs[(wr0 + m) * 132 + k0];
        const float* ph = &hs[(wr0 + m) * 132 + k0];
        short8 a;
        #pragma unroll
        for (int j = 0; j < 8; j++) a[j] = f2bs(pc[j] - ph[j]);
        #pragma unroll
        for (int ct = 0; ct < 8; ct++) {
            short8 b = *(const short8*)&BTe3[(ct * 16 + m) * 128 + k0];
            acc[ct] = __builtin_amdgcn_mfma_f32_16x16x32_bf16(a, b, acc[ct], 0, 0, 0);
        }
    }
    #pragma unroll
    for (int ct = 0; ct < 8; ct++) {
        int col = ct * 16 + m;
        #pragma unroll
        for (int rg = 0; rg < 4; rg++) {
            int rl = wr0 + q * 4 + rg;
            float td = fmaxf(acc[ct][rg] + btd[col], 0.0f);
            h1s[rl * 132 + col] = cs[rl * 132 + col] + td;
        }
    }
    __syncthreads();

    #pragma unroll
    for (int it = 0; it < 8; it++) {
        int idx = it * 128 + tid;
        int r = idx >> 5, c4 = (idx & 31) * 4;
        *(float4*)&outp[(long)(row0 + r) * HDIM + c4] = *(float4*)&h1s[r * 132 + c4];
    }
}

// ---------------------------------------------------------------------------
extern "C" void kernel_launch(void* const* d_in, const int* in_sizes, int n_in,
                              void* d_out, int out_size, void* d_ws, size_t ws_size,
                              hipStream_t stream)
{
    const int* src = (const int*)d_in[0];
    const int* dst = (const int*)d_in[1];
    const int* ety = (const int*)d_in[2];
    const float* dyn     = (const float*)d_in[3];
    const float* emb_rel = (const float*)d_in[4];
    const float* Wn1     = (const float*)d_in[5];
    const float* Wl1     = (const float*)d_in[6];
    const float* Wn2     = (const float*)d_in[7];
    const float* Wl2     = (const float*)d_in[8];
    const float* gWx     = (const float*)d_in[9];
    const float* gWh     = (const float*)d_in[10];
    const float* gbx     = (const float*)d_in[11];
    const float* gbh     = (const float*)d_in[12];
    const float* gateW   = (const float*)d_in[13];
    const float* gateb   = (const float*)d_in[14];
    const float* tdW     = (const float*)d_in[15];
    const float* tdb     = (const float*)d_in[16];
    const float* tgW     = (const float*)d_in[17];
    const float* tgb     = (const float*)d_in[18];

    const long NH = (long)N_ENT * HDIM;          // 12,800,000
    float* ws = (float*)d_ws;
    long off = 0;
    float* A    = ws + off; off += NH;           // h state
    float* B    = ws + off; off += NH;           // layer1 out
    float* rel  = ws + off; off += (long)NR * HDIM;
    float* WxT  = ws + off; off += 98304;
    float* WhT  = ws + off; off += 49152;
    short* BT1  = (short*)(ws + off); off += 16384;   // 128x256 bf16
    short* BT2  = (short*)(ws + off); off += 16384;
    short* BTe1 = (short*)(ws + off); off += 8192;    // 128x128 bf16
    short* BTe2 = (short*)(ws + off); off += 16384;
    short* BTe3 = (short*)(ws + off); off += 8192;
    int* rowptr = (int*)(ws + off); off += NPAD;
    int* cnt    = (int*)(ws + off); off += NPAD;      // cnt, cnt2 contiguous
    int* cnt2   = (int*)(ws + off); off += NPAD;
    int* eidx   = (int*)(ws + off); off += 200704;
    int* bsum   = (int*)(ws + off); off += 128;
    float* agg  = ws + off;                      // chunk*128 floats
    float* C    = (float*)d_out;                 // layer2 out (= cur)

    const long avail = (long)(ws_size / 4) - off;
    const int cand[5] = {100000, 50000, 25008, 12512, 6256};
    int chunk = -1;
    for (int c = 0; c < 5; c++)
        if (avail >= (long)cand[c] * HDIM) { chunk = cand[c]; break; }

    if (chunk < 0) {
        diag_kernel<<<1, 64, 0, stream>>>((float*)d_out, (float)ws_size);
        return;
    }

    prep_kernel<<<256, 256, 0, stream>>>(
        emb_rel, gWx, gWh, Wn1, Wl1, Wn2, Wl2, tgW, gateW, tdW,
        rel, WxT, WhT, BT1, BT2, BTe1, BTe2, BTe3);

    norm_init_kernel<<<N_ENT, 64, 0, stream>>>(dyn, A);

    const int egrid = (NE + 255) / 256;          // 782 blocks
    const int fe_grid = N_ENT / 32;              // 3125 blocks

    for (int t = 0; t < NSTEP; t++) {
        const int* st = src + (long)t * NE;
        const int* dt = dst + (long)t * NE;
        const int* et = ety + (long)t * NE;

        // ---- CSR build for this step's graph (shared by both layers)
        zero_int_kernel<<<(2 * NPAD + 255) / 256, 256, 0, stream>>>(cnt, 2 * NPAD);
        hist_kernel<<<egrid, 256, 0, stream>>>(dt, cnt);
        scan1_kernel<<<SCAN_NB, 256, 0, stream>>>(cnt, rowptr, bsum);
        scan2_kernel<<<1, 128, 0, stream>>>(bsum, SCAN_NB);
        scan3_kernel<<<SCAN_NB, 256, 0, stream>>>(rowptr, bsum);
        fill_kernel<<<egrid, 256, 0, stream>>>(dt, rowptr, cnt2, eidx);

        gru_kernel<<<NR, 128, 0, stream>>>(rel, emb_rel, WxT, WhT, gbx, gbh);

        // layer 1: A -> B
        for (int lo = 0; lo < N_ENT; lo += chunk) {
            int hi = lo + chunk > N_ENT ? N_ENT : lo + chunk;
            gather_kernel<<<((hi - lo) * 128 + 255) / 256, 256, 0, stream>>>(
                st, et, eidx, rowptr, A, rel, agg, lo, hi);
            layer_gemm<<<(hi - lo + 255) / 256, 256, 0, stream>>>(
                agg, A, BT1, B, lo, hi);
        }
        // layer 2: B -> C
        for (int lo = 0; lo < N_ENT; lo += chunk) {
            int hi = lo + chunk > N_ENT ? N_ENT : lo + chunk;
            gather_kernel<<<((hi - lo) * 128 + 255) / 256, 256, 0, stream>>>(
                st, et, eidx, rowptr, B, rel, agg, lo, hi);
            layer_gemm<<<(hi - lo + 255) / 256, 256, 0, stream>>>(
                agg, B, BT2, C, lo, hi);
        }

        // fused epilogue: (C, A) -> A (t<3) or d_out == C (t=3)
        float* outp = (t == NSTEP - 1) ? C : A;
        fused_epi_kernel<<<fe_grid, 128, 0, stream>>>(
            C, A, BTe1, BTe2, BTe3, tgb, gateb, tdb, outp);
    }
}

// Round 8
// 1668.150 us; speedup vs baseline: 1.1448x; 1.0696x over previous
//
#include <hip/hip_runtime.h>
#include <hip/hip_bf16.h>

#define N_ENT 100000
#define HDIM 128
#define NE 200000
#define NR 460
#define NSTEP 4
#define SLOPE 0.22916666666666666f
#define NPAD 100352            // N_ENT padded to 1024 multiple (98*1024)
#define SCAN_NB 98

typedef __attribute__((ext_vector_type(8))) short short8;
typedef __attribute__((ext_vector_type(4))) float f32x4;

__device__ __forceinline__ float sigm(float x) { return 1.0f / (1.0f + __expf(-x)); }
__device__ __forceinline__ short f2bs(float f) {
    __hip_bfloat16 b = __float2bfloat16(f);
    short s; __builtin_memcpy(&s, &b, 2); return s;
}

// ---------------------------------------------------------------------------
__global__ void zero_int_kernel(int* __restrict__ p, int n)
{
    int i = blockIdx.x * 256 + threadIdx.x;
    if (i < n) p[i] = 0;
}

__global__ void diag_kernel(float* o, float v)
{
    if (threadIdx.x == 0) o[0] = v;
}

// ---------------------------------------------------------------------------
// CSR build: histogram -> 3-phase exclusive scan -> fill
// ---------------------------------------------------------------------------
__global__ void hist_kernel(const int* __restrict__ dst, int* __restrict__ cnt)
{
    int e = blockIdx.x * 256 + threadIdx.x;
    if (e < NE) atomicAdd(&cnt[dst[e]], 1);
}

__global__ __launch_bounds__(256)
void scan1_kernel(const int* __restrict__ cnt, int* __restrict__ rowptr,
                  int* __restrict__ bsum)
{
    __shared__ int ts[256];
    int b = blockIdx.x, t = threadIdx.x;
    int base = b * 1024 + t * 4;
    int4 v = *(const int4*)&cnt[base];
    int s = v.x + v.y + v.z + v.w;
    ts[t] = s;
    __syncthreads();
    for (int off = 1; off < 256; off <<= 1) {
        int x = 0;
        if (t >= off) x = ts[t - off];
        __syncthreads();
        if (t >= off) ts[t] += x;
        __syncthreads();
    }
    int excl = ts[t] - s;
    if (t == 255) bsum[b] = ts[t];
    rowptr[base + 0] = excl;
    rowptr[base + 1] = excl + v.x;
    rowptr[base + 2] = excl + v.x + v.y;
    rowptr[base + 3] = excl + v.x + v.y + v.z;
}

__global__ __launch_bounds__(128)
void scan2_kernel(int* __restrict__ bsum, int nb)
{
    __shared__ int ts[128];
    int t = threadIdx.x;
    int v = (t < nb) ? bsum[t] : 0;
    ts[t] = v;
    __syncthreads();
    for (int off = 1; off < 128; off <<= 1) {
        int x = 0;
        if (t >= off) x = ts[t - off];
        __syncthreads();
        if (t >= off) ts[t] += x;
        __syncthreads();
    }
    if (t < nb) bsum[t] = ts[t] - v;   // exclusive
}

__global__ __launch_bounds__(256)
void scan3_kernel(int* __restrict__ rowptr, const int* __restrict__ bsum)
{
    int b = blockIdx.x, t = threadIdx.x;
    int add = bsum[b];
    int base = b * 1024 + t * 4;
    rowptr[base + 0] += add;
    rowptr[base + 1] += add;
    rowptr[base + 2] += add;
    rowptr[base + 3] += add;
}

__global__ void fill_kernel(const int* __restrict__ dst,
                            const int* __restrict__ rowptr,
                            int* __restrict__ c2, int* __restrict__ eidx)
{
    int e = blockIdx.x * 256 + threadIdx.x;
    if (e < NE) {
        int d = dst[e];
        int p = atomicAdd(&c2[d], 1);
        eidx[rowptr[d] + p] = e;
    }
}

// ---------------------------------------------------------------------------
// Prep: GRU weight transposes (f32) + bf16 B^T buffers for the MFMA GEMMs.
// ---------------------------------------------------------------------------
__global__ void prep_kernel(
    const float* __restrict__ emb_rel,
    const float* __restrict__ Wx, const float* __restrict__ Wh,
    const float* __restrict__ Wn1, const float* __restrict__ Wl1,
    const float* __restrict__ Wn2, const float* __restrict__ Wl2,
    const float* __restrict__ tgW, const float* __restrict__ gateW,
    const float* __restrict__ tdW,
    float* __restrict__ rel,
    float* __restrict__ WxT, float* __restrict__ WhT,
    short* __restrict__ BT1, short* __restrict__ BT2,
    short* __restrict__ BTe1, short* __restrict__ BTe2,
    short* __restrict__ BTe3)
{
    int tid = blockIdx.x * blockDim.x + threadIdx.x;
    int nthr = gridDim.x * blockDim.x;
    for (int i = tid; i < NR * HDIM; i += nthr)
        rel[i] = emb_rel[i];
    for (int i = tid; i < 384 * 256; i += nthr) {
        int r = i >> 8, c = i & 255;
        WxT[c * 384 + r] = Wx[i];
    }
    for (int i = tid; i < 384 * 128; i += nthr) {
        int r = i >> 7, c = i & 127;
        WhT[c * 384 + r] = Wh[i];
    }
    for (int i = tid; i < 128 * 256; i += nthr) {   // layer BTs: [x|h]@[Wn;Wl]
        int n = i >> 8, k = i & 255;
        float v1 = (k < 128) ? Wn1[k * 128 + n] : Wl1[(k - 128) * 128 + n];
        float v2 = (k < 128) ? Wn2[k * 128 + n] : Wl2[(k - 128) * 128 + n];
        BT1[n * 256 + k] = f2bs(v1);
        BT2[n * 256 + k] = f2bs(v2);
    }
    for (int i = tid; i < 128 * 128; i += nthr) {   // E1 (transpose), E3 (direct)
        int n = i >> 7, k = i & 127;
        BTe1[n * 128 + k] = f2bs(tgW[k * 128 + n]);
        BTe3[n * 128 + k] = f2bs(tdW[n * 128 + k]);
    }
    for (int i = tid; i < 128 * 256; i += nthr) {   // E2 (direct)
        int n = i >> 8, k = i & 255;
        BTe2[n * 256 + k] = f2bs(gateW[n * 256 + k]);
    }
}

// ---------------------------------------------------------------------------
// h0 = l2norm(dynamic_emb); one wave per row.
// ---------------------------------------------------------------------------
__global__ __launch_bounds__(64)
void norm_init_kernel(const float* __restrict__ emb, float* __restrict__ h)
{
    int row = blockIdx.x, lane = threadIdx.x;
    float v0 = emb[row * HDIM + lane];
    float v1 = emb[row * HDIM + 64 + lane];
    float s = v0 * v0 + v1 * v1;
    #pragma unroll
    for (int off = 32; off; off >>= 1) s += __shfl_xor(s, off);
    float invn = 1.0f / fmaxf(sqrtf(s), 1e-12f);
    h[row * HDIM + lane] = v0 * invn;
    h[row * HDIM + 64 + lane] = v1 * invn;
}

// ---------------------------------------------------------------------------
// GRUCell relation evolution (f32 GEMV — tiny: 460 rows).
// ---------------------------------------------------------------------------
__global__ __launch_bounds__(128)
void gru_kernel(float* rel, const float* __restrict__ emb_rel,
                const float* __restrict__ WxT, const float* __restrict__ WhT,
                const float* __restrict__ bx, const float* __restrict__ bh)
{
    __shared__ __align__(16) float x[256];
    __shared__ __align__(16) float hh[128];
    int b = blockIdx.x, j = threadIdx.x;
    float hj = rel[b * HDIM + j];
    x[j] = emb_rel[b * HDIM + j];
    x[128 + j] = hj;
    hh[j] = hj;
    __syncthreads();
    float xr = 0, xz = 0, xn = 0, hr = 0, hz = 0, hn = 0;
    for (int k = 0; k < 256; k++) {
        float xv = x[k];
        const float* w = &WxT[k * 384];
        xr += xv * w[j]; xz += xv * w[128 + j]; xn += xv * w[256 + j];
    }
    for (int k = 0; k < 128; k++) {
        float hv = hh[k];
        const float* w = &WhT[k * 384];
        hr += hv * w[j]; hz += hv * w[128 + j]; hn += hv * w[256 + j];
    }
    float r = sigm(xr + bx[j] + hr + bh[j]);
    float z = sigm(xz + bx[128 + j] + hz + bh[128 + j]);
    float n = tanhf(xn + bx[256 + j] + r * (hn + bh[256 + j]));
    rel[b * HDIM + j] = (1.0f - z) * n + z * hj;
}

// ---------------------------------------------------------------------------
// CSR gather for rows [lo,hi): agg[r-lo] = (sum_e h[src]+rel[et]) / max(deg,1).
// ---------------------------------------------------------------------------
__global__ __launch_bounds__(256)
void gather_kernel(const int* __restrict__ src, const int* __restrict__ et,
                   const int* __restrict__ eidx, const int* __restrict__ rowptr,
                   const float* __restrict__ hin, const float* __restrict__ rel,
                   float* __restrict__ agg, int lo, int hi)
{
    int idx = blockIdx.x * 256 + threadIdx.x;
    int r = lo + (idx >> 7);
    int i = idx & 127;
    if (r >= hi) return;
    int p0 = rowptr[r], p1 = rowptr[r + 1];
    float v = 0.0f;
    for (int p = p0; p < p1; p++) {
        int e = eidx[p];
        int s = src[e], rt = et[e];
        v += hin[(long)s * HDIM + i] + rel[rt * HDIM + i];
    }
    float rdeg = (p1 > p0) ? 1.0f / (float)(p1 - p0) : 0.0f;
    agg[(long)(r - lo) * HDIM + i] = v * rdeg;
}

// ---------------------------------------------------------------------------
// Layer MFMA GEMM: out = rrelu([agg | h] @ BT^T).  agg pre-normalized.
// ---------------------------------------------------------------------------
__global__ __launch_bounds__(256, 2)
void layer_gemm(const float* __restrict__ agg, const float* __restrict__ hin,
                const short* __restrict__ BTg, float* __restrict__ out,
                int lo, int hi)
{
    __shared__ short bt[128][264];     // 256 + 8 pad
    const int tid = threadIdx.x;
    for (int i = tid * 8; i < 128 * 256; i += 256 * 8) {
        int n = i >> 8, k = i & 255;
        *(short8*)&bt[n][k] = *(const short8*)&BTg[i];
    }
    __syncthreads();

    const int lane = tid & 63;
    const int wv = tid >> 6;
    const int m = lane & 15, q = lane >> 4;
    const int rowBase = lo + blockIdx.x * 256 + wv * 64;

    f32x4 acc[4][8];
    #pragma unroll
    for (int rt = 0; rt < 4; rt++)
        #pragma unroll
        for (int ct = 0; ct < 8; ct++)
            acc[rt][ct] = (f32x4)0.0f;

    for (int kc = 0; kc < 8; kc++) {
        short8 a[4];
        #pragma unroll
        for (int rt = 0; rt < 4; rt++) {
            int row = rowBase + rt * 16 + m;
            float v[8];
            if (row < hi) {
                int k0 = kc * 32 + q * 8;
                const float* p = (kc < 4) ? &agg[(long)(row - lo) * HDIM + k0]
                                          : &hin[(long)row * HDIM + (k0 - 128)];
                float4 u0 = *(const float4*)p;
                float4 u1 = *(const float4*)(p + 4);
                v[0]=u0.x; v[1]=u0.y; v[2]=u0.z; v[3]=u0.w;
                v[4]=u1.x; v[5]=u1.y; v[6]=u1.z; v[7]=u1.w;
            } else {
                #pragma unroll
                for (int i = 0; i < 8; i++) v[i] = 0.0f;
            }
            short8 t;
            #pragma unroll
            for (int i = 0; i < 8; i++) t[i] = f2bs(v[i]);
            a[rt] = t;
        }
        short8 b[8];
        #pragma unroll
        for (int ct = 0; ct < 8; ct++)
            b[ct] = *(const short8*)&bt[ct * 16 + m][kc * 32 + q * 8];
        #pragma unroll
        for (int rt = 0; rt < 4; rt++)
            #pragma unroll
            for (int ct = 0; ct < 8; ct++)
                acc[rt][ct] = __builtin_amdgcn_mfma_f32_16x16x32_bf16(
                    a[rt], b[ct], acc[rt][ct], 0, 0, 0);
    }

    #pragma unroll
    for (int rt = 0; rt < 4; rt++) {
        #pragma unroll
        for (int rg = 0; rg < 4; rg++) {
            int row = rowBase + rt * 16 + q * 4 + rg;
            if (row >= hi) continue;
            #pragma unroll
            for (int ct = 0; ct < 8; ct++) {
                int col = ct * 16 + m;
                float c = acc[rt][ct][rg];
                c = c >= 0.0f ? c : SLOPE * c;
                out[(long)row * HDIM + col] = c;
            }
        }
    }
}

// ---------------------------------------------------------------------------
// Fused epilogue v2 — occupancy-focused rework:
//   * 2 LDS buffers (cur/h; h1,h2,out overwrite cur in place) = 33.8 KB
//   * 256 threads, 4 waves; wave owns 16 rows x 64 cols (4 col-tiles)
//   * barriers separate every MFMA read phase from in-place writes
// -> 4 blocks/CU x 4 waves = 16 waves/CU (50%), vs 6 waves (14.9%) before.
// ---------------------------------------------------------------------------
__global__ __launch_bounds__(256)
void fused_epi_kernel(const float* __restrict__ cur, const float* __restrict__ hprev,
                      const short* __restrict__ BTe1, const short* __restrict__ BTe2,
                      const short* __restrict__ BTe3,
                      const float* __restrict__ bt, const float* __restrict__ bg,
                      const float* __restrict__ btd,
                      float* __restrict__ outp)
{
    __shared__ __align__(16) float cs[32 * 132];   // cur -> h1 -> h2 -> out
    __shared__ __align__(16) float hs[32 * 132];   // h (constant)
    __shared__ float invn_s[32];
    const int tid = threadIdx.x;
    const int row0 = blockIdx.x * 32;

    #pragma unroll
    for (int it = 0; it < 4; it++) {
        int idx = it * 256 + tid;                  // 0..1023 float4 slots
        int r = idx >> 5, c4 = (idx & 31) * 4;
        *(float4*)&cs[r * 132 + c4] = *(const float4*)&cur[(long)(row0 + r) * HDIM + c4];
        *(float4*)&hs[r * 132 + c4] = *(const float4*)&hprev[(long)(row0 + r) * HDIM + c4];
    }
    __syncthreads();

    const int wv = tid >> 6, lane = tid & 63;
    const int m = lane & 15, q = lane >> 4;
    const int wr0 = (wv >> 1) * 16;                // wave's row base (0 or 16)
    const int ct0 = (wv & 1) * 4;                  // wave's col-tile base

    // row inverse norms: wave wv handles rows wv*8 .. wv*8+7
    #pragma unroll
    for (int r = 0; r < 8; r++) {
        int rr = wv * 8 + r;
        float a = cs[rr * 132 + lane];
        float b = cs[rr * 132 + 64 + lane];
        float s = a * a + b * b;
        #pragma unroll
        for (int off = 32; off; off >>= 1) s += __shfl_xor(s, off);
        if (lane == 0) invn_s[rr] = 1.0f / fmaxf(sqrtf(s), 1e-12f);
    }
    __syncthreads();

    const float sA = invn_s[wr0 + m];

    // ---- E1 MFMA: acc = (cur_n) @ Wt  (A rows wr0+m, cols of ct0..ct0+3)
    f32x4 acc[4];
    #pragma unroll
    for (int ct = 0; ct < 4; ct++) acc[ct] = (f32x4)0.0f;
    #pragma unroll
    for (int kc = 0; kc < 4; kc++) {
        int k0 = kc * 32 + q * 8;
        const float* p = &cs[(wr0 + m) * 132 + k0];
        float4 u0 = *(const float4*)p;
        float4 u1 = *(const float4*)(p + 4);
        short8 a;
        a[0]=f2bs(u0.x*sA); a[1]=f2bs(u0.y*sA); a[2]=f2bs(u0.z*sA); a[3]=f2bs(u0.w*sA);
        a[4]=f2bs(u1.x*sA); a[5]=f2bs(u1.y*sA); a[6]=f2bs(u1.z*sA); a[7]=f2bs(u1.w*sA);
        #pragma unroll
        for (int ct = 0; ct < 4; ct++) {
            short8 b = *(const short8*)&BTe1[((ct0 + ct) * 16 + m) * 128 + k0];
            acc[ct] = __builtin_amdgcn_mfma_f32_16x16x32_bf16(a, b, acc[ct], 0, 0, 0);
        }
    }
    __syncthreads();   // all cur reads done before in-place h1 writes

    #pragma unroll
    for (int ct = 0; ct < 4; ct++) {
        int col = (ct0 + ct) * 16 + m;
        #pragma unroll
        for (int rg = 0; rg < 4; rg++) {
            int rl = wr0 + q * 4 + rg;
            float tw = sigm(acc[ct][rg] + bt[col]);
            float curn = cs[rl * 132 + col] * invn_s[rl];
            float hv = hs[rl * 132 + col];
            cs[rl * 132 + col] = tw * curn + (1.0f - tw) * hv;   // h1
        }
    }
    __syncthreads();

    // ---- E2 MFMA: acc = [h1|h] @ Wg^T
    #pragma unroll
    for (int ct = 0; ct < 4; ct++) acc[ct] = (f32x4)0.0f;
    #pragma unroll
    for (int kc = 0; kc < 8; kc++) {
        int k0 = kc * 32 + q * 8;
        const float* p = (kc < 4) ? &cs[(wr0 + m) * 132 + k0]
                                  : &hs[(wr0 + m) * 132 + (k0 - 128)];
        float4 u0 = *(const float4*)p;
        float4 u1 = *(const float4*)(p + 4);
        short8 a;
        a[0]=f2bs(u0.x); a[1]=f2bs(u0.y); a[2]=f2bs(u0.z); a[3]=f2bs(u0.w);
        a[4]=f2bs(u1.x); a[5]=f2bs(u1.y); a[6]=f2bs(u1.z); a[7]=f2bs(u1.w);
        #pragma unroll
        for (int ct = 0; ct < 4; ct++) {
            short8 b = *(const short8*)&BTe2[((ct0 + ct) * 16 + m) * 256 + k0];
            acc[ct] = __builtin_amdgcn_mfma_f32_16x16x32_bf16(a, b, acc[ct], 0, 0, 0);
        }
    }
    __syncthreads();   // all h1 reads done

    #pragma unroll
    for (int ct = 0; ct < 4; ct++) {
        int col = (ct0 + ct) * 16 + m;
        #pragma unroll
        for (int rg = 0; rg < 4; rg++) {
            int rl = wr0 + q * 4 + rg;
            float g = sigm(acc[ct][rg] + bg[col]);
            float h1v = cs[rl * 132 + col];
            cs[rl * 132 + col] = g * h1v + (1.0f - g) * hs[rl * 132 + col];  // h2
        }
    }
    __syncthreads();

    // ---- E3 MFMA: acc = (h2 - h) @ Wtd^T
    #pragma unroll
    for (int ct = 0; ct < 4; ct++) acc[ct] = (f32x4)0.0f;
    #pragma unroll
    for (int kc = 0; kc < 4; kc++) {
        int k0 = kc * 32 + q * 8;
        const float* pc = &cs[(wr0 + m) * 132 + k0];
        const float* ph = &hs[(wr0 + m) * 132 + k0];
        float4 c0 = *(const float4*)pc;
        float4 c1 = *(const float4*)(pc + 4);
        float4 h0 = *(const float4*)ph;
        float4 h1 = *(const float4*)(ph + 4);
        short8 a;
        a[0]=f2bs(c0.x-h0.x); a[1]=f2bs(c0.y-h0.y); a[2]=f2bs(c0.z-h0.z); a[3]=f2bs(c0.w-h0.w);
        a[4]=f2bs(c1.x-h1.x); a[5]=f2bs(c1.y-h1.y); a[6]=f2bs(c1.z-h1.z); a[7]=f2bs(c1.w-h1.w);
        #pragma unroll
        for (int ct = 0; ct < 4; ct++) {
            short8 b = *(const short8*)&BTe3[((ct0 + ct) * 16 + m) * 128 + k0];
            acc[ct] = __builtin_amdgcn_mfma_f32_16x16x32_bf16(a, b, acc[ct], 0, 0, 0);
        }
    }
    __syncthreads();   // all h2 reads done

    #pragma unroll
    for (int ct = 0; ct < 4; ct++) {
        int col = (ct0 + ct) * 16 + m;
        #pragma unroll
        for (int rg = 0; rg < 4; rg++) {
            int rl = wr0 + q * 4 + rg;
            float td = fmaxf(acc[ct][rg] + btd[col], 0.0f);
            cs[rl * 132 + col] = cs[rl * 132 + col] + td;        // out
        }
    }
    __syncthreads();

    #pragma unroll
    for (int it = 0; it < 4; it++) {
        int idx = it * 256 + tid;
        int r = idx >> 5, c4 = (idx & 31) * 4;
        *(float4*)&outp[(long)(row0 + r) * HDIM + c4] = *(float4*)&cs[r * 132 + c4];
    }
}

// ---------------------------------------------------------------------------
extern "C" void kernel_launch(void* const* d_in, const int* in_sizes, int n_in,
                              void* d_out, int out_size, void* d_ws, size_t ws_size,
                              hipStream_t stream)
{
    const int* src = (const int*)d_in[0];
    const int* dst = (const int*)d_in[1];
    const int* ety = (const int*)d_in[2];
    const float* dyn     = (const float*)d_in[3];
    const float* emb_rel = (const float*)d_in[4];
    const float* Wn1     = (const float*)d_in[5];
    const float* Wl1     = (const float*)d_in[6];
    const float* Wn2     = (const float*)d_in[7];
    const float* Wl2     = (const float*)d_in[8];
    const float* gWx     = (const float*)d_in[9];
    const float* gWh     = (const float*)d_in[10];
    const float* gbx     = (const float*)d_in[11];
    const float* gbh     = (const float*)d_in[12];
    const float* gateW   = (const float*)d_in[13];
    const float* gateb   = (const float*)d_in[14];
    const float* tdW     = (const float*)d_in[15];
    const float* tdb     = (const float*)d_in[16];
    const float* tgW     = (const float*)d_in[17];
    const float* tgb     = (const float*)d_in[18];

    const long NH = (long)N_ENT * HDIM;          // 12,800,000
    float* ws = (float*)d_ws;
    long off = 0;
    float* A    = ws + off; off += NH;           // h state
    float* B    = ws + off; off += NH;           // layer1 out
    float* rel  = ws + off; off += (long)NR * HDIM;
    float* WxT  = ws + off; off += 98304;
    float* WhT  = ws + off; off += 49152;
    short* BT1  = (short*)(ws + off); off += 16384;   // 128x256 bf16
    short* BT2  = (short*)(ws + off); off += 16384;
    short* BTe1 = (short*)(ws + off); off += 8192;    // 128x128 bf16
    short* BTe2 = (short*)(ws + off); off += 16384;
    short* BTe3 = (short*)(ws + off); off += 8192;
    int* rowptr = (int*)(ws + off); off += NPAD;
    int* cnt    = (int*)(ws + off); off += NPAD;      // cnt, cnt2 contiguous
    int* cnt2   = (int*)(ws + off); off += NPAD;
    int* eidx   = (int*)(ws + off); off += 200704;
    int* bsum   = (int*)(ws + off); off += 128;
    float* agg  = ws + off;                      // chunk*128 floats
    float* C    = (float*)d_out;                 // layer2 out (= cur)

    const long avail = (long)(ws_size / 4) - off;
    const int cand[5] = {100000, 50000, 25008, 12512, 6256};
    int chunk = -1;
    for (int c = 0; c < 5; c++)
        if (avail >= (long)cand[c] * HDIM) { chunk = cand[c]; break; }

    if (chunk < 0) {
        diag_kernel<<<1, 64, 0, stream>>>((float*)d_out, (float)ws_size);
        return;
    }

    prep_kernel<<<256, 256, 0, stream>>>(
        emb_rel, gWx, gWh, Wn1, Wl1, Wn2, Wl2, tgW, gateW, tdW,
        rel, WxT, WhT, BT1, BT2, BTe1, BTe2, BTe3);

    norm_init_kernel<<<N_ENT, 64, 0, stream>>>(dyn, A);

    const int egrid = (NE + 255) / 256;          // 782 blocks
    const int fe_grid = N_ENT / 32;              // 3125 blocks

    for (int t = 0; t < NSTEP; t++) {
        const int* st = src + (long)t * NE;
        const int* dt = dst + (long)t * NE;
        const int* et = ety + (long)t * NE;

        // ---- CSR build for this step's graph (shared by both layers)
        zero_int_kernel<<<(2 * NPAD + 255) / 256, 256, 0, stream>>>(cnt, 2 * NPAD);
        hist_kernel<<<egrid, 256, 0, stream>>>(dt, cnt);
        scan1_kernel<<<SCAN_NB, 256, 0, stream>>>(cnt, rowptr, bsum);
        scan2_kernel<<<1, 128, 0, stream>>>(bsum, SCAN_NB);
        scan3_kernel<<<SCAN_NB, 256, 0, stream>>>(rowptr, bsum);
        fill_kernel<<<egrid, 256, 0, stream>>>(dt, rowptr, cnt2, eidx);

        gru_kernel<<<NR, 128, 0, stream>>>(rel, emb_rel, WxT, WhT, gbx, gbh);

        // layer 1: A -> B
        for (int lo = 0; lo < N_ENT; lo += chunk) {
            int hi = lo + chunk > N_ENT ? N_ENT : lo + chunk;
            gather_kernel<<<((hi - lo) * 128 + 255) / 256, 256, 0, stream>>>(
                st, et, eidx, rowptr, A, rel, agg, lo, hi);
            layer_gemm<<<(hi - lo + 255) / 256, 256, 0, stream>>>(
                agg, A, BT1, B, lo, hi);
        }
        // layer 2: B -> C
        for (int lo = 0; lo < N_ENT; lo += chunk) {
            int hi = lo + chunk > N_ENT ? N_ENT : lo + chunk;
            gather_kernel<<<((hi - lo) * 128 + 255) / 256, 256, 0, stream>>>(
                st, et, eidx, rowptr, B, rel, agg, lo, hi);
            layer_gemm<<<(hi - lo + 255) / 256, 256, 0, stream>>>(
                agg, B, BT2, C, lo, hi);
        }

        // fused epilogue: (C, A) -> A (t<3) or d_out == C (t=3)
        float* outp = (t == NSTEP - 1) ? C : A;
        fused_epi_kernel<<<fe_grid, 256, 0, stream>>>(
            C, A, BTe1, BTe2, BTe3, tgb, gateb, tdb, outp);
    }
}

// Round 9
// 1445.540 us; speedup vs baseline: 1.3211x; 1.1540x over previous
//
#include <hip/hip_runtime.h>
#include <hip/hip_bf16.h>

#define N_ENT 100000
#define HDIM 128
#define NE 200000
#define NR 460
#define NSTEP 4
#define SLOPE 0.22916666666666666f
#define NPAD 100352            // N_ENT padded to 1024 multiple (98*1024)
#define SCAN_NB 98

typedef __attribute__((ext_vector_type(8))) short short8;
typedef __attribute__((ext_vector_type(4))) float f32x4;

__device__ __forceinline__ float sigm(float x) { return 1.0f / (1.0f + __expf(-x)); }
__device__ __forceinline__ short f2bs(float f) {
    __hip_bfloat16 b = __float2bfloat16(f);
    short s; __builtin_memcpy(&s, &b, 2); return s;
}
__device__ __forceinline__ float bs2f(short s) {
    union { unsigned int u; float f; } c;
    c.u = ((unsigned int)(unsigned short)s) << 16;
    return c.f;
}

// ---------------------------------------------------------------------------
__global__ void zero_int_kernel(int* __restrict__ p, int n)
{
    int i = blockIdx.x * 256 + threadIdx.x;
    if (i < n) p[i] = 0;
}

__global__ void diag_kernel(float* o, float v)
{
    if (threadIdx.x == 0) o[0] = v;
}

// ---------------------------------------------------------------------------
// CSR build: histogram -> 3-phase exclusive scan -> fill
// ---------------------------------------------------------------------------
__global__ void hist_kernel(const int* __restrict__ dst, int* __restrict__ cnt)
{
    int e = blockIdx.x * 256 + threadIdx.x;
    if (e < NE) atomicAdd(&cnt[dst[e]], 1);
}

__global__ __launch_bounds__(256)
void scan1_kernel(const int* __restrict__ cnt, int* __restrict__ rowptr,
                  int* __restrict__ bsum)
{
    __shared__ int ts[256];
    int b = blockIdx.x, t = threadIdx.x;
    int base = b * 1024 + t * 4;
    int4 v = *(const int4*)&cnt[base];
    int s = v.x + v.y + v.z + v.w;
    ts[t] = s;
    __syncthreads();
    for (int off = 1; off < 256; off <<= 1) {
        int x = 0;
        if (t >= off) x = ts[t - off];
        __syncthreads();
        if (t >= off) ts[t] += x;
        __syncthreads();
    }
    int excl = ts[t] - s;
    if (t == 255) bsum[b] = ts[t];
    rowptr[base + 0] = excl;
    rowptr[base + 1] = excl + v.x;
    rowptr[base + 2] = excl + v.x + v.y;
    rowptr[base + 3] = excl + v.x + v.y + v.z;
}

__global__ __launch_bounds__(128)
void scan2_kernel(int* __restrict__ bsum, int nb)
{
    __shared__ int ts[128];
    int t = threadIdx.x;
    int v = (t < nb) ? bsum[t] : 0;
    ts[t] = v;
    __syncthreads();
    for (int off = 1; off < 128; off <<= 1) {
        int x = 0;
        if (t >= off) x = ts[t - off];
        __syncthreads();
        if (t >= off) ts[t] += x;
        __syncthreads();
    }
    if (t < nb) bsum[t] = ts[t] - v;   // exclusive
}

__global__ __launch_bounds__(256)
void scan3_kernel(int* __restrict__ rowptr, const int* __restrict__ bsum)
{
    int b = blockIdx.x, t = threadIdx.x;
    int add = bsum[b];
    int base = b * 1024 + t * 4;
    rowptr[base + 0] += add;
    rowptr[base + 1] += add;
    rowptr[base + 2] += add;
    rowptr[base + 3] += add;
}

__global__ void fill_kernel(const int* __restrict__ dst,
                            const int* __restrict__ rowptr,
                            int* __restrict__ c2, int* __restrict__ eidx)
{
    int e = blockIdx.x * 256 + threadIdx.x;
    if (e < NE) {
        int d = dst[e];
        int p = atomicAdd(&c2[d], 1);
        eidx[rowptr[d] + p] = e;
    }
}

// ---------------------------------------------------------------------------
// Prep: GRU weight transposes (f32) + bf16 B^T buffers for the MFMA GEMMs.
// ---------------------------------------------------------------------------
__global__ void prep_kernel(
    const float* __restrict__ emb_rel,
    const float* __restrict__ Wx, const float* __restrict__ Wh,
    const float* __restrict__ Wn1, const float* __restrict__ Wl1,
    const float* __restrict__ Wn2, const float* __restrict__ Wl2,
    const float* __restrict__ tgW, const float* __restrict__ gateW,
    const float* __restrict__ tdW,
    float* __restrict__ rel,
    float* __restrict__ WxT, float* __restrict__ WhT,
    short* __restrict__ BT1, short* __restrict__ BT2,
    short* __restrict__ BTe1, short* __restrict__ BTe2,
    short* __restrict__ BTe3)
{
    int tid = blockIdx.x * blockDim.x + threadIdx.x;
    int nthr = gridDim.x * blockDim.x;
    for (int i = tid; i < NR * HDIM; i += nthr)
        rel[i] = emb_rel[i];
    for (int i = tid; i < 384 * 256; i += nthr) {
        int r = i >> 8, c = i & 255;
        WxT[c * 384 + r] = Wx[i];
    }
    for (int i = tid; i < 384 * 128; i += nthr) {
        int r = i >> 7, c = i & 127;
        WhT[c * 384 + r] = Wh[i];
    }
    for (int i = tid; i < 128 * 256; i += nthr) {   // layer BTs: [x|h]@[Wn;Wl]
        int n = i >> 8, k = i & 255;
        float v1 = (k < 128) ? Wn1[k * 128 + n] : Wl1[(k - 128) * 128 + n];
        float v2 = (k < 128) ? Wn2[k * 128 + n] : Wl2[(k - 128) * 128 + n];
        BT1[n * 256 + k] = f2bs(v1);
        BT2[n * 256 + k] = f2bs(v2);
    }
    for (int i = tid; i < 128 * 128; i += nthr) {   // E1 (transpose), E3 (direct)
        int n = i >> 7, k = i & 127;
        BTe1[n * 128 + k] = f2bs(tgW[k * 128 + n]);
        BTe3[n * 128 + k] = f2bs(tdW[n * 128 + k]);
    }
    for (int i = tid; i < 128 * 256; i += nthr) {   // E2 (direct)
        int n = i >> 8, k = i & 255;
        BTe2[n * 256 + k] = f2bs(gateW[n * 256 + k]);
    }
}

// ---------------------------------------------------------------------------
// h0 = l2norm(dynamic_emb); one wave per row.
// ---------------------------------------------------------------------------
__global__ __launch_bounds__(64)
void norm_init_kernel(const float* __restrict__ emb, float* __restrict__ h)
{
    int row = blockIdx.x, lane = threadIdx.x;
    float v0 = emb[row * HDIM + lane];
    float v1 = emb[row * HDIM + 64 + lane];
    float s = v0 * v0 + v1 * v1;
    #pragma unroll
    for (int off = 32; off; off >>= 1) s += __shfl_xor(s, off);
    float invn = 1.0f / fmaxf(sqrtf(s), 1e-12f);
    h[row * HDIM + lane] = v0 * invn;
    h[row * HDIM + 64 + lane] = v1 * invn;
}

// ---------------------------------------------------------------------------
// GRUCell relation evolution (f32 GEMV — tiny: 460 rows).
// ---------------------------------------------------------------------------
__global__ __launch_bounds__(128)
void gru_kernel(float* rel, const float* __restrict__ emb_rel,
                const float* __restrict__ WxT, const float* __restrict__ WhT,
                const float* __restrict__ bx, const float* __restrict__ bh)
{
    __shared__ __align__(16) float x[256];
    __shared__ __align__(16) float hh[128];
    int b = blockIdx.x, j = threadIdx.x;
    float hj = rel[b * HDIM + j];
    x[j] = emb_rel[b * HDIM + j];
    x[128 + j] = hj;
    hh[j] = hj;
    __syncthreads();
    float xr = 0, xz = 0, xn = 0, hr = 0, hz = 0, hn = 0;
    for (int k = 0; k < 256; k++) {
        float xv = x[k];
        const float* w = &WxT[k * 384];
        xr += xv * w[j]; xz += xv * w[128 + j]; xn += xv * w[256 + j];
    }
    for (int k = 0; k < 128; k++) {
        float hv = hh[k];
        const float* w = &WhT[k * 384];
        hr += hv * w[j]; hz += hv * w[128 + j]; hn += hv * w[256 + j];
    }
    float r = sigm(xr + bx[j] + hr + bh[j]);
    float z = sigm(xz + bx[128 + j] + hz + bh[128 + j]);
    float n = tanhf(xn + bx[256 + j] + r * (hn + bh[256 + j]));
    rel[b * HDIM + j] = (1.0f - z) * n + z * hj;
}

// ---------------------------------------------------------------------------
// CSR gather for rows [lo,hi): aggb[r-lo] = bf16((sum_e h[src]+rel[et])/deg).
// One thread per (row, 2 dims); 64 threads per row; packed 4B stores.
// ---------------------------------------------------------------------------
__global__ __launch_bounds__(256)
void gather_kernel(const int* __restrict__ src, const int* __restrict__ et,
                   const int* __restrict__ eidx, const int* __restrict__ rowptr,
                   const float* __restrict__ hin, const float* __restrict__ rel,
                   short* __restrict__ aggb, int lo, int hi)
{
    int idx = blockIdx.x * 256 + threadIdx.x;
    int r = lo + (idx >> 6);
    int i2 = (idx & 63) * 2;
    if (r >= hi) return;
    int p0 = rowptr[r], p1 = rowptr[r + 1];
    float v0 = 0.0f, v1 = 0.0f;
    for (int p = p0; p < p1; p++) {
        int e = eidx[p];
        int s = src[e], rt = et[e];
        const float* ph = &hin[(long)s * HDIM + i2];
        const float* pr = &rel[rt * HDIM + i2];
        v0 += ph[0] + pr[0];
        v1 += ph[1] + pr[1];
    }
    float rdeg = (p1 > p0) ? 1.0f / (float)(p1 - p0) : 0.0f;
    unsigned int pk = (unsigned int)(unsigned short)f2bs(v0 * rdeg)
                    | ((unsigned int)(unsigned short)f2bs(v1 * rdeg) << 16);
    *(unsigned int*)&aggb[(long)(r - lo) * HDIM + i2] = pk;
}

// ---------------------------------------------------------------------------
// Layer MFMA GEMM: out = rrelu([aggb | h] @ BT^T).  aggb bf16 (direct
// A-fragments, no conversion); B-fragments from L2-hot global (no LDS).
// ---------------------------------------------------------------------------
__global__ __launch_bounds__(256, 2)
void layer_gemm(const short* __restrict__ aggb, const float* __restrict__ hin,
                const short* __restrict__ BTg, float* __restrict__ out,
                int lo, int hi)
{
    const int tid = threadIdx.x;
    const int lane = tid & 63;
    const int wv = tid >> 6;
    const int m = lane & 15, q = lane >> 4;
    const int rowBase = lo + blockIdx.x * 256 + wv * 64;

    f32x4 acc[4][8];
    #pragma unroll
    for (int rt = 0; rt < 4; rt++)
        #pragma unroll
        for (int ct = 0; ct < 8; ct++)
            acc[rt][ct] = (f32x4)0.0f;

    for (int kc = 0; kc < 8; kc++) {
        short8 a[4];
        #pragma unroll
        for (int rt = 0; rt < 4; rt++) {
            int row = rowBase + rt * 16 + m;
            int k0 = kc * 32 + q * 8;
            if (row < hi) {
                if (kc < 4) {
                    a[rt] = *(const short8*)&aggb[(long)(row - lo) * HDIM + k0];
                } else {
                    const float* p = &hin[(long)row * HDIM + (k0 - 128)];
                    float4 u0 = *(const float4*)p;
                    float4 u1 = *(const float4*)(p + 4);
                    short8 t;
                    t[0]=f2bs(u0.x); t[1]=f2bs(u0.y); t[2]=f2bs(u0.z); t[3]=f2bs(u0.w);
                    t[4]=f2bs(u1.x); t[5]=f2bs(u1.y); t[6]=f2bs(u1.z); t[7]=f2bs(u1.w);
                    a[rt] = t;
                }
            } else {
                short8 t;
                #pragma unroll
                for (int i = 0; i < 8; i++) t[i] = 0;
                a[rt] = t;
            }
        }
        short8 b[8];
        #pragma unroll
        for (int ct = 0; ct < 8; ct++)
            b[ct] = *(const short8*)&BTg[(ct * 16 + m) * 256 + kc * 32 + q * 8];
        #pragma unroll
        for (int rt = 0; rt < 4; rt++)
            #pragma unroll
            for (int ct = 0; ct < 8; ct++)
                acc[rt][ct] = __builtin_amdgcn_mfma_f32_16x16x32_bf16(
                    a[rt], b[ct], acc[rt][ct], 0, 0, 0);
    }

    #pragma unroll
    for (int rt = 0; rt < 4; rt++) {
        #pragma unroll
        for (int rg = 0; rg < 4; rg++) {
            int row = rowBase + rt * 16 + q * 4 + rg;
            if (row >= hi) continue;
            #pragma unroll
            for (int ct = 0; ct < 8; ct++) {
                int col = ct * 16 + m;
                float c = acc[rt][ct][rg];
                c = c >= 0.0f ? c : SLOPE * c;
                out[(long)row * HDIM + col] = c;
            }
        }
    }
}

// ---------------------------------------------------------------------------
// Fused epilogue v3 — bf16 LDS:
//   cs = bf16(cur*invn) -> h1 -> h2;  hs = bf16(h);  ds = bf16(h2-h)
//   A-fragments are raw short8 LDS loads (no per-stage conversion).
//   f32 output staged via overlay on dead hs/ds region for coalesced stores.
// LDS 26.1 KB -> 6 blocks/CU x 4 waves = 75% occupancy.
// ---------------------------------------------------------------------------
#define ER 32                  // rows per block
#define ES 136                 // bf16 row stride (shorts)
__global__ __launch_bounds__(256)
void fused_epi_kernel(const float* __restrict__ cur, const float* __restrict__ hprev,
                      const short* __restrict__ BTe1, const short* __restrict__ BTe2,
                      const short* __restrict__ BTe3,
                      const float* __restrict__ bt, const float* __restrict__ bg,
                      const float* __restrict__ btd,
                      float* __restrict__ outp)
{
    __shared__ __align__(16) short sm[3 * ER * ES];   // cs | hs | ds
    __shared__ float invn_s[ER];
    short* cs = sm;
    short* hs = sm + ER * ES;
    short* ds = sm + 2 * ER * ES;
    float* fout = (float*)(sm + ER * ES);             // overlay on hs+ds
    const int tid = threadIdx.x;
    const int row0 = blockIdx.x * ER;

    // stage cur/h as bf16: 512 slots of 8 elems each
    #pragma unroll
    for (int it = 0; it < 2; it++) {
        int s = it * 256 + tid;
        int r = s >> 4, c8 = (s & 15) * 8;
        const float* pc = &cur[(long)(row0 + r) * HDIM + c8];
        const float* ph = &hprev[(long)(row0 + r) * HDIM + c8];
        float4 c0 = *(const float4*)pc, c1 = *(const float4*)(pc + 4);
        float4 h0 = *(const float4*)ph, h1 = *(const float4*)(ph + 4);
        short8 tc, th;
        tc[0]=f2bs(c0.x); tc[1]=f2bs(c0.y); tc[2]=f2bs(c0.z); tc[3]=f2bs(c0.w);
        tc[4]=f2bs(c1.x); tc[5]=f2bs(c1.y); tc[6]=f2bs(c1.z); tc[7]=f2bs(c1.w);
        th[0]=f2bs(h0.x); th[1]=f2bs(h0.y); th[2]=f2bs(h0.z); th[3]=f2bs(h0.w);
        th[4]=f2bs(h1.x); th[5]=f2bs(h1.y); th[6]=f2bs(h1.z); th[7]=f2bs(h1.w);
        *(short8*)&cs[r * ES + c8] = tc;
        *(short8*)&hs[r * ES + c8] = th;
    }
    __syncthreads();

    const int wv = tid >> 6, lane = tid & 63;
    const int m = lane & 15, q = lane >> 4;
    const int wr0 = (wv >> 1) * 16;                // wave's row base (0 or 16)
    const int ct0 = (wv & 1) * 4;                  // wave's col-tile base

    // row inverse norms: wave wv handles rows wv*8..wv*8+7
    #pragma unroll
    for (int r = 0; r < 8; r++) {
        int rr = wv * 8 + r;
        float a = bs2f(cs[rr * ES + lane]);
        float b = bs2f(cs[rr * ES + 64 + lane]);
        float s = a * a + b * b;
        #pragma unroll
        for (int off = 32; off; off >>= 1) s += __shfl_xor(s, off);
        if (lane == 0) invn_s[rr] = 1.0f / fmaxf(sqrtf(s), 1e-12f);
    }
    __syncthreads();

    // scale pass: cs <- bf16(cur * invn)  (cur_n)
    #pragma unroll
    for (int it = 0; it < 2; it++) {
        int s = it * 256 + tid;
        int r = s >> 4, c8 = (s & 15) * 8;
        float inv = invn_s[r];
        short8 x = *(short8*)&cs[r * ES + c8];
        short8 y;
        #pragma unroll
        for (int j = 0; j < 8; j++) y[j] = f2bs(bs2f(x[j]) * inv);
        *(short8*)&cs[r * ES + c8] = y;
    }
    __syncthreads();

    // ---- E1: acc = cur_n @ Wt
    f32x4 acc[4];
    #pragma unroll
    for (int ct = 0; ct < 4; ct++) acc[ct] = (f32x4)0.0f;
    #pragma unroll
    for (int kc = 0; kc < 4; kc++) {
        int k0 = kc * 32 + q * 8;
        short8 a = *(const short8*)&cs[(wr0 + m) * ES + k0];
        #pragma unroll
        for (int ct = 0; ct < 4; ct++) {
            short8 b = *(const short8*)&BTe1[((ct0 + ct) * 16 + m) * 128 + k0];
            acc[ct] = __builtin_amdgcn_mfma_f32_16x16x32_bf16(a, b, acc[ct], 0, 0, 0);
        }
    }
    __syncthreads();

    #pragma unroll
    for (int ct = 0; ct < 4; ct++) {
        int col = (ct0 + ct) * 16 + m;
        #pragma unroll
        for (int rg = 0; rg < 4; rg++) {
            int rl = wr0 + q * 4 + rg;
            float tw = sigm(acc[ct][rg] + bt[col]);
            float curn = bs2f(cs[rl * ES + col]);
            float hv = bs2f(hs[rl * ES + col]);
            cs[rl * ES + col] = f2bs(tw * curn + (1.0f - tw) * hv);   // h1
        }
    }
    __syncthreads();

    // ---- E2: acc = [h1|h] @ Wg^T
    #pragma unroll
    for (int ct = 0; ct < 4; ct++) acc[ct] = (f32x4)0.0f;
    #pragma unroll
    for (int kc = 0; kc < 8; kc++) {
        int k0 = kc * 32 + q * 8;
        short8 a = (kc < 4) ? *(const short8*)&cs[(wr0 + m) * ES + k0]
                            : *(const short8*)&hs[(wr0 + m) * ES + (k0 - 128)];
        #pragma unroll
        for (int ct = 0; ct < 4; ct++) {
            short8 b = *(const short8*)&BTe2[((ct0 + ct) * 16 + m) * 256 + k0];
            acc[ct] = __builtin_amdgcn_mfma_f32_16x16x32_bf16(a, b, acc[ct], 0, 0, 0);
        }
    }
    __syncthreads();

    #pragma unroll
    for (int ct = 0; ct < 4; ct++) {
        int col = (ct0 + ct) * 16 + m;
        #pragma unroll
        for (int rg = 0; rg < 4; rg++) {
            int rl = wr0 + q * 4 + rg;
            float g = sigm(acc[ct][rg] + bg[col]);
            float h1v = bs2f(cs[rl * ES + col]);
            float hv = bs2f(hs[rl * ES + col]);
            float h2 = g * h1v + (1.0f - g) * hv;
            cs[rl * ES + col] = f2bs(h2);              // h2
            ds[rl * ES + col] = f2bs(h2 - hv);         // d
        }
    }
    __syncthreads();

    // ---- E3: acc = d @ Wtd^T
    #pragma unroll
    for (int ct = 0; ct < 4; ct++) acc[ct] = (f32x4)0.0f;
    #pragma unroll
    for (int kc = 0; kc < 4; kc++) {
        int k0 = kc * 32 + q * 8;
        short8 a = *(const short8*)&ds[(wr0 + m) * ES + k0];
        #pragma unroll
        for (int ct = 0; ct < 4; ct++) {
            short8 b = *(const short8*)&BTe3[((ct0 + ct) * 16 + m) * 128 + k0];
            acc[ct] = __builtin_amdgcn_mfma_f32_16x16x32_bf16(a, b, acc[ct], 0, 0, 0);
        }
    }
    __syncthreads();   // last hs/ds reads done; fout overlay becomes safe

    #pragma unroll
    for (int ct = 0; ct < 4; ct++) {
        int col = (ct0 + ct) * 16 + m;
        #pragma unroll
        for (int rg = 0; rg < 4; rg++) {
            int rl = wr0 + q * 4 + rg;
            float td = fmaxf(acc[ct][rg] + btd[col], 0.0f);
            fout[rl * 132 + col] = bs2f(cs[rl * ES + col]) + td;
        }
    }
    __syncthreads();

    #pragma unroll
    for (int it = 0; it < 4; it++) {
        int idx = it * 256 + tid;
        int r = idx >> 5, c4 = (idx & 31) * 4;
        *(float4*)&outp[(long)(row0 + r) * HDIM + c4] = *(float4*)&fout[r * 132 + c4];
    }
}

// ---------------------------------------------------------------------------
extern "C" void kernel_launch(void* const* d_in, const int* in_sizes, int n_in,
                              void* d_out, int out_size, void* d_ws, size_t ws_size,
                              hipStream_t stream)
{
    const int* src = (const int*)d_in[0];
    const int* dst = (const int*)d_in[1];
    const int* ety = (const int*)d_in[2];
    const float* dyn     = (const float*)d_in[3];
    const float* emb_rel = (const float*)d_in[4];
    const float* Wn1     = (const float*)d_in[5];
    const float* Wl1     = (const float*)d_in[6];
    const float* Wn2     = (const float*)d_in[7];
    const float* Wl2     = (const float*)d_in[8];
    const float* gWx     = (const float*)d_in[9];
    const float* gWh     = (const float*)d_in[10];
    const float* gbx     = (const float*)d_in[11];
    const float* gbh     = (const float*)d_in[12];
    const float* gateW   = (const float*)d_in[13];
    const float* gateb   = (const float*)d_in[14];
    const float* tdW     = (const float*)d_in[15];
    const float* tdb     = (const float*)d_in[16];
    const float* tgW     = (const float*)d_in[17];
    const float* tgb     = (const float*)d_in[18];

    const long NH = (long)N_ENT * HDIM;          // 12,800,000
    float* ws = (float*)d_ws;
    long off = 0;
    float* A    = ws + off; off += NH;           // h state
    float* B    = ws + off; off += NH;           // layer1 out
    float* rel  = ws + off; off += (long)NR * HDIM;
    float* WxT  = ws + off; off += 98304;
    float* WhT  = ws + off; off += 49152;
    short* BT1  = (short*)(ws + off); off += 16384;   // 128x256 bf16
    short* BT2  = (short*)(ws + off); off += 16384;
    short* BTe1 = (short*)(ws + off); off += 8192;    // 128x128 bf16
    short* BTe2 = (short*)(ws + off); off += 16384;
    short* BTe3 = (short*)(ws + off); off += 8192;
    int* rowptr = (int*)(ws + off); off += NPAD;
    int* cnt    = (int*)(ws + off); off += NPAD;      // cnt, cnt2 contiguous
    int* cnt2   = (int*)(ws + off); off += NPAD;
    int* eidx   = (int*)(ws + off); off += 200704;
    int* bsum   = (int*)(ws + off); off += 128;
    short* aggb = (short*)(ws + off);            // chunk*128 bf16
    float* C    = (float*)d_out;                 // layer2 out (= cur)

    const long avail = (long)(ws_size / 4) - off;
    const int cand[5] = {100000, 50000, 25008, 12512, 6256};
    int chunk = -1;
    for (int c = 0; c < 5; c++)
        if (avail >= (long)cand[c] * 64) { chunk = cand[c]; break; }

    if (chunk < 0) {
        diag_kernel<<<1, 64, 0, stream>>>((float*)d_out, (float)ws_size);
        return;
    }

    prep_kernel<<<256, 256, 0, stream>>>(
        emb_rel, gWx, gWh, Wn1, Wl1, Wn2, Wl2, tgW, gateW, tdW,
        rel, WxT, WhT, BT1, BT2, BTe1, BTe2, BTe3);

    norm_init_kernel<<<N_ENT, 64, 0, stream>>>(dyn, A);

    const int egrid = (NE + 255) / 256;          // 782 blocks
    const int fe_grid = N_ENT / 32;              // 3125 blocks

    for (int t = 0; t < NSTEP; t++) {
        const int* st = src + (long)t * NE;
        const int* dt = dst + (long)t * NE;
        const int* et = ety + (long)t * NE;

        // ---- CSR build for this step's graph (shared by both layers)
        zero_int_kernel<<<(2 * NPAD + 255) / 256, 256, 0, stream>>>(cnt, 2 * NPAD);
        hist_kernel<<<egrid, 256, 0, stream>>>(dt, cnt);
        scan1_kernel<<<SCAN_NB, 256, 0, stream>>>(cnt, rowptr, bsum);
        scan2_kernel<<<1, 128, 0, stream>>>(bsum, SCAN_NB);
        scan3_kernel<<<SCAN_NB, 256, 0, stream>>>(rowptr, bsum);
        fill_kernel<<<egrid, 256, 0, stream>>>(dt, rowptr, cnt2, eidx);

        gru_kernel<<<NR, 128, 0, stream>>>(rel, emb_rel, WxT, WhT, gbx, gbh);

        // layer 1: A -> B
        for (int lo = 0; lo < N_ENT; lo += chunk) {
            int hi = lo + chunk > N_ENT ? N_ENT : lo + chunk;
            gather_kernel<<<((hi - lo) * 64 + 255) / 256, 256, 0, stream>>>(
                st, et, eidx, rowptr, A, rel, aggb, lo, hi);
            layer_gemm<<<(hi - lo + 255) / 256, 256, 0, stream>>>(
                aggb, A, BT1, B, lo, hi);
        }
        // layer 2: B -> C
        for (int lo = 0; lo < N_ENT; lo += chunk) {
            int hi = lo + chunk > N_ENT ? N_ENT : lo + chunk;
            gather_kernel<<<((hi - lo) * 64 + 255) / 256, 256, 0, stream>>>(
                st, et, eidx, rowptr, B, rel, aggb, lo, hi);
            layer_gemm<<<(hi - lo + 255) / 256, 256, 0, stream>>>(
                aggb, B, BT2, C, lo, hi);
        }

        // fused epilogue: (C, A) -> A (t<3) or d_out == C (t=3)
        float* outp = (t == NSTEP - 1) ? C : A;
        fused_epi_kernel<<<fe_grid, 256, 0, stream>>>(
            C, A, BTe1, BTe2, BTe3, tgb, gateb, tdb, outp);
    }
}